// Round 7
// baseline (1011.235 us; speedup 1.0000x reference)
//
#include <hip/hip_runtime.h>
#include <math.h>

typedef __bf16 bf16;
typedef __bf16 bf16x8 __attribute__((ext_vector_type(8)));
typedef __bf16 bf16x4 __attribute__((ext_vector_type(4)));
typedef __bf16 bf16x2 __attribute__((ext_vector_type(2)));
typedef float f32x4 __attribute__((ext_vector_type(4)));

__device__ __forceinline__ float sigmoid_(float x) { return 1.f / (1.f + __expf(-x)); }
__device__ __forceinline__ f32x4 mfma16(bf16x8 a, bf16x8 b, f32x4 c) {
  return __builtin_amdgcn_mfma_f32_16x16x32_bf16(a, b, c, 0, 0, 0);
}

// async global->LDS, 16B per lane. LDS dest must be wave-uniform base + lane*16.
#define GLD16(ldsp, gp)                                                        \
  __builtin_amdgcn_global_load_lds(                                            \
      (__attribute__((address_space(1))) void*)(gp),                           \
      (__attribute__((address_space(3))) void*)(ldsp), 16, 0, 0)

enum { M_F32 = 0, M_BF16 = 1, M_BF16_RELU = 2, M_SIG = 3, M_SIG_NEG = 4,
       M_TANH = 5, M_QUV = 6, M_ZR = 7, M_SHIFT = 8 };

struct GemmP {
  const bf16* A; const bf16* B;
  bf16* Cb; bf16* Cb2; float* Cf; float* Cf2;
  const float* bias; const float* up; const float* vp;
  int K, lda, ldb, ldc;
  long long Abat, Bbat, Cbat;
  int mode, S, Ksl;
};

// ---- GEMM v5: barrier-free, direct global->register MFMA fragments --------
// Block 128x64 (4 waves, wave 32x64). No LDS, no __syncthreads: prefetch
// distance 1 in registers -> compiler emits fine-grained vmcnt (never 0).
// B in (N,K) layout. Requires niters (=Ksl/64) even and >= 2.
__global__ __launch_bounds__(256) void gemm_v5(GemmP p) {
  const int tid = threadIdx.x;
  const int wave = tid >> 6, lane = tid & 63;
  const int g = lane >> 4, ln = lane & 15;
  const int bz = blockIdx.z;
  const int batch = bz / p.S, slice = bz % p.S;
  const bf16* A = p.A + (long long)batch * p.Abat + (long long)slice * p.Ksl;
  const bf16* B = p.B + (long long)batch * p.Bbat + (long long)slice * p.Ksl;
  const int m0 = blockIdx.x * 128 + wave * 32;
  const int n0 = blockIdx.y * 64;
  const bf16* aBase = A + (long long)(m0 + ln) * p.lda + g * 8;
  const bf16* bBase = B + (long long)(n0 + ln) * p.ldb + g * 8;
  const int niters = p.Ksl >> 6;
  const int kmax = p.Ksl - 64;

  bf16x8 A0[2][2], B0[4][2], A1[2][2], B1[4][2];
  f32x4 acc[2][4] = {};

#define LOADF(Af, Bf, k0)                                                      \
  {                                                                            \
    int kk = (k0);                                                             \
    _Pragma("unroll") for (int mi = 0; mi < 2; mi++)                           \
      _Pragma("unroll") for (int kh = 0; kh < 2; kh++)                         \
        Af[mi][kh] = *(const bf16x8*)(aBase + (long long)mi * 16 * p.lda + kk + kh * 32); \
    _Pragma("unroll") for (int ni = 0; ni < 4; ni++)                           \
      _Pragma("unroll") for (int kh = 0; kh < 2; kh++)                         \
        Bf[ni][kh] = *(const bf16x8*)(bBase + (long long)ni * 16 * p.ldb + kk + kh * 32); \
  }

#define MFMAF(Af, Bf)                                                          \
  _Pragma("unroll") for (int kh = 0; kh < 2; kh++)                             \
    _Pragma("unroll") for (int mi = 0; mi < 2; mi++)                           \
      _Pragma("unroll") for (int ni = 0; ni < 4; ni++)                         \
        acc[mi][ni] = mfma16(Af[mi][kh], Bf[ni][kh], acc[mi][ni]);

  LOADF(A0, B0, 0)
  for (int it = 0; it < niters; it += 2) {
    int k1 = (it + 1) << 6; if (k1 > kmax) k1 = kmax;
    LOADF(A1, B1, k1)
    MFMAF(A0, B0)
    int k2 = (it + 2) << 6; if (k2 > kmax) k2 = kmax;
    LOADF(A0, B0, k2)
    MFMAF(A1, B1)
  }
#undef LOADF
#undef MFMAF

  const long long cb = (long long)bz * p.Cbat;
  const bool part = (p.S > 1);
#pragma unroll
  for (int mi = 0; mi < 2; mi++) {
#pragma unroll
    for (int r = 0; r < 4; r++) {
      int row = m0 + mi * 16 + g * 4 + r;
      long long ro = cb + (long long)row * p.ldc;
#pragma unroll
      for (int ni = 0; ni < 4; ni++) {
        int col = n0 + ni * 16 + ln;
        float a = acc[mi][ni][r];
        if (part) { p.Cf[ro + col] = a; continue; }
        float bv = p.bias ? p.bias[col] : 0.f;
        switch (p.mode) {
          case M_F32: p.Cf[ro + col] = a + bv; break;
          case M_BF16: p.Cb[ro + col] = (bf16)(a + bv); break;
          case M_BF16_RELU: { float t = a + bv; p.Cb[ro + col] = (bf16)(t > 0.f ? t : 0.f); } break;
          case M_SIG: p.Cf[ro + col] = sigmoid_(a + bv); break;
          case M_SIG_NEG: p.Cf[ro + col] = sigmoid_(a - bv); break;
          case M_TANH: p.Cf[ro + col] = tanhf(a + bv); break;
          case M_QUV: {
            float t = a + bv;
            p.Cb[ro + col] = (bf16)(t + p.up[col]);
            p.Cb2[ro + col] = (bf16)(t + p.vp[col]);
          } break;
          case M_ZR: {
            if (col < 1024) p.Cf[(long long)row * 1024 + col] = sigmoid_(a - p.bias[col]);
            else p.Cf2[(long long)row * 1024 + col - 1024] = sigmoid_(a);
          } break;
          default: break;
        }
      }
    }
  }
}

// ---------------- GEMM v4 (kept for M_SHIFT): BK=64, GLD16 dbuf, swizzled ---
template <int BM, int BN, int T>
__global__ __launch_bounds__(T, 2) void gemm_v4(GemmP p) {
  constexpr int AISS = BM * 8 / T;
  constexpr int BISS = BN * 8 / T;
  constexpr int NW = T / 64;
  constexpr int WCOLS = (BN == 128) ? 2 : 1;
  constexpr int WROWS = NW / WCOLS;
  constexpr int MI = BM / (WROWS * 16);
  __shared__ bf16 smem[2 * (BM + BN) * 64];
  bf16* Asm = smem;
  bf16* Bsm = smem + 2 * BM * 64;
  const int tid = threadIdx.x;
  const int wave = tid >> 6, lane = tid & 63;
  const int g = lane >> 4, ln = lane & 15;
  const int wr = wave / WCOLS;
  const int wc = wave % WCOLS;
  const int bz = blockIdx.z;
  const int batch = bz / p.S, slice = bz % p.S;
  const bf16* A = p.A + (long long)batch * p.Abat + (long long)slice * p.Ksl;
  const bf16* B = p.B + (long long)batch * p.Bbat + (long long)slice * p.Ksl;
  const int m0 = blockIdx.x * BM, n0 = blockIdx.y * BN;
  const int niters = p.Ksl >> 6;

  auto issue = [&](int buf, int k0) {
#pragma unroll
    for (int j = 0; j < AISS; j++) {
      int i = tid + T * j;
      int r = i >> 3, c = (i & 7) ^ (r & 7);
      GLD16(Asm + buf * BM * 64 + i * 8, A + (long long)(m0 + r) * p.lda + k0 + c * 8);
    }
#pragma unroll
    for (int j = 0; j < BISS; j++) {
      int i = tid + T * j;
      int r = i >> 3, c = (i & 7) ^ (r & 7);
      GLD16(Bsm + buf * BN * 64 + i * 8, B + (long long)(n0 + r) * p.ldb + k0 + c * 8);
    }
  };

  f32x4 acc[MI][4] = {};
  issue(0, 0);
  __syncthreads();
  for (int it = 0; it < niters; it++) {
    if (it + 1 < niters) issue((it + 1) & 1, (it + 1) << 6);
    const bf16* as = Asm + (it & 1) * BM * 64;
    const bf16* bs = Bsm + (it & 1) * BN * 64;
    bf16x8 af[MI][2], bfm[4][2];
#pragma unroll
    for (int mi = 0; mi < MI; mi++) {
      int row = wr * (16 * MI) + mi * 16 + ln;
#pragma unroll
      for (int kh = 0; kh < 2; kh++) {
        int ch = (kh * 4 + g) ^ (row & 7);
        af[mi][kh] = *(const bf16x8*)(as + row * 64 + ch * 8);
      }
    }
#pragma unroll
    for (int ni = 0; ni < 4; ni++) {
      int row = wc * 64 + ni * 16 + ln;
#pragma unroll
      for (int kh = 0; kh < 2; kh++) {
        int ch = (kh * 4 + g) ^ (row & 7);
        bfm[ni][kh] = *(const bf16x8*)(bs + row * 64 + ch * 8);
      }
    }
#pragma unroll
    for (int kh = 0; kh < 2; kh++)
#pragma unroll
      for (int mi = 0; mi < MI; mi++)
#pragma unroll
        for (int ni = 0; ni < 4; ni++)
          acc[mi][ni] = mfma16(af[mi][kh], bfm[ni][kh], acc[mi][ni]);
    __syncthreads();
  }

  const long long cb = (long long)bz * p.Cbat;

  // M_SHIFT: LDS-transposed, alignment-split vectorized shifted store.
  if constexpr (BM == 64 && BN == 64) {
    if (p.mode == M_SHIFT) {
      float* Ct = (float*)smem;  // 64 x 65 f32
#pragma unroll
      for (int mi = 0; mi < MI; mi++)
#pragma unroll
        for (int r = 0; r < 4; r++) {
          int row = wave * 32 + mi * 16 + g * 4 + r;
#pragma unroll
          for (int ni = 0; ni < 4; ni++)
            Ct[row * 65 + ni * 16 + ln] = acc[mi][ni][r];
        }
      __syncthreads();
      int row = tid & 63;
      int c0 = (tid >> 6) * 32;
      int m = m0 + row;
      int q = m >> 2;
      long long ro = cb + (long long)m * p.ldc;
      bf16* dst = p.Cb + ro;
      const float* src = Ct + row * 65 + c0;
      int kstart = n0 + c0 - 511 + q;
      int idx = (kstart < 0) ? -kstart : 0;
      if (idx < 32) {
        int k = kstart + idx;
        if (k & 1) { dst[k] = (bf16)src[idx]; idx++; k++; }
        if ((k & 2) && idx + 1 < 32) {
          bf16x2 o; o[0] = (bf16)src[idx]; o[1] = (bf16)src[idx + 1];
          *(bf16x2*)(dst + k) = o; idx += 2; k += 2;
        }
        for (; idx + 3 < 32; idx += 4, k += 4) {
          bf16x4 o;
          o[0] = (bf16)src[idx];     o[1] = (bf16)src[idx + 1];
          o[2] = (bf16)src[idx + 2]; o[3] = (bf16)src[idx + 3];
          *(bf16x4*)(dst + k) = o;
        }
        if (idx + 1 < 32) {
          bf16x2 o; o[0] = (bf16)src[idx]; o[1] = (bf16)src[idx + 1];
          *(bf16x2*)(dst + k) = o; idx += 2; k += 2;
        }
        if (idx < 32) dst[k] = (bf16)src[idx];
      }
      return;
    }
  }

  const bool part = (p.S > 1);
#pragma unroll
  for (int mi = 0; mi < MI; mi++) {
#pragma unroll
    for (int r = 0; r < 4; r++) {
      int row = m0 + wr * (16 * MI) + mi * 16 + g * 4 + r;
      long long ro = cb + (long long)row * p.ldc;
#pragma unroll
      for (int ni = 0; ni < 4; ni++) {
        int col = n0 + wc * 64 + ni * 16 + ln;
        float a = acc[mi][ni][r];
        if (part) { p.Cf[ro + col] = a; continue; }
        float bv = p.bias ? p.bias[col] : 0.f;
        switch (p.mode) {
          case M_F32: p.Cf[ro + col] = a + bv; break;
          case M_BF16: p.Cb[ro + col] = (bf16)(a + bv); break;
          case M_BF16_RELU: { float t = a + bv; p.Cb[ro + col] = (bf16)(t > 0.f ? t : 0.f); } break;
          case M_SIG: p.Cf[ro + col] = sigmoid_(a + bv); break;
          case M_SIG_NEG: p.Cf[ro + col] = sigmoid_(a - bv); break;
          case M_TANH: p.Cf[ro + col] = tanhf(a + bv); break;
          case M_QUV: {
            float t = a + bv;
            p.Cb[ro + col] = (bf16)(t + p.up[col]);
            p.Cb2[ro + col] = (bf16)(t + p.vp[col]);
          } break;
          case M_ZR: {
            if (col < 1024) p.Cf[(long long)row * 1024 + col] = sigmoid_(a - p.bias[col]);
            else p.Cf2[(long long)row * 1024 + col - 1024] = sigmoid_(a);
          } break;
          default: break;
        }
      }
    }
  }
}

// split-K=2 partial reduce + epilogue
__global__ void reduce2(const float* p0, const float* p1, const float* bias,
                        bf16* ob, float* of, int ldc, int mode, int n) {
  int i = (blockIdx.x * 256 + threadIdx.x) * 4;
  if (i >= n) return;
  float4 a = *(const float4*)(p0 + i);
  float4 b = *(const float4*)(p1 + i);
  int row = i >> 10, col = i & 1023;
  float v0 = a.x + b.x, v1 = a.y + b.y, v2 = a.z + b.z, v3 = a.w + b.w;
  if (bias) { v0 += bias[col]; v1 += bias[col + 1]; v2 += bias[col + 2]; v3 += bias[col + 3]; }
  if (mode == M_TANH) {
    float4 o = {tanhf(v0), tanhf(v1), tanhf(v2), tanhf(v3)};
    *(float4*)(of + (size_t)row * ldc + col) = o;
  } else {
    bf16x4 o;
    o[0] = (bf16)(v0 > 0.f ? v0 : 0.f); o[1] = (bf16)(v1 > 0.f ? v1 : 0.f);
    o[2] = (bf16)(v2 > 0.f ? v2 : 0.f); o[3] = (bf16)(v3 > 0.f ? v3 : 0.f);
    *(bf16x4*)(ob + (size_t)row * ldc + col) = o;
  }
}

// ---------------- weight transpose + fp32->bf16 convert ----------------
struct TDesc { const float* src; bf16* dst; int K, N, ldd; };
struct TPack { TDesc d[18]; };

__global__ __launch_bounds__(256) void wt_transpose(TPack tp) {
  TDesc t = tp.d[blockIdx.z];
  int ntx = t.N >> 6, nty = t.K >> 6;
  int tile = blockIdx.x;
  if (tile >= ntx * nty) return;
  int k0 = (tile / ntx) * 64, n0 = (tile % ntx) * 64;
  __shared__ bf16 tb[64][72];
  int tid = threadIdx.x;
  int tr = tid >> 4, tc = (tid & 15) * 4;
#pragma unroll
  for (int ph = 0; ph < 4; ph++) {
    int k = k0 + ph * 16 + tr;
    float4 vv = *(const float4*)(t.src + (size_t)k * t.N + n0 + tc);
    tb[tc + 0][ph * 16 + tr] = (bf16)vv.x;
    tb[tc + 1][ph * 16 + tr] = (bf16)vv.y;
    tb[tc + 2][ph * 16 + tr] = (bf16)vv.z;
    tb[tc + 3][ph * 16 + tr] = (bf16)vv.w;
  }
  __syncthreads();
#pragma unroll
  for (int ph = 0; ph < 4; ph++) {
    int n = ph * 16 + tr;
    bf16x4 o;
    o[0] = tb[n][tc + 0]; o[1] = tb[n][tc + 1]; o[2] = tb[n][tc + 2]; o[3] = tb[n][tc + 3];
    *(bf16x4*)(t.dst + (size_t)(n0 + n) * t.ldd + k0 + tc) = o;
  }
}

__global__ void convertf2b(const float* src, bf16* dst, int n) {
  int i = (blockIdx.x * 256 + threadIdx.x) * 4;
  if (i >= n) return;
  float4 vv = *(const float4*)(src + i);
  bf16x4 o; o[0] = (bf16)vv.x; o[1] = (bf16)vv.y; o[2] = (bf16)vv.z; o[3] = (bf16)vv.w;
  *(bf16x4*)(dst + i) = o;
}

// ---------------- LayerNorm 1 (concat(memory, inputs)) ----------------
__global__ __launch_bounds__(256) void ln1_kernel(const float* inputs, const float* memory,
                                                  const float* g, const float* b,
                                                  bf16* x1, bf16* acat1x) {
  int row = blockIdx.x;
  int tid = threadIdx.x;
  const float* src = (row < 2048) ? (memory + (size_t)row * 1024)
                                  : (inputs + (size_t)(row - 2048) * 1024);
  float4 vv = *(const float4*)(src + tid * 4);
  float s = vv.x + vv.y + vv.z + vv.w;
  float s2 = vv.x * vv.x + vv.y * vv.y + vv.z * vv.z + vv.w * vv.w;
#pragma unroll
  for (int off = 1; off < 64; off <<= 1) { s += __shfl_xor(s, off, 64); s2 += __shfl_xor(s2, off, 64); }
  __shared__ float red[8];
  int wave = tid >> 6, lane = tid & 63;
  if (lane == 0) { red[wave] = s; red[4 + wave] = s2; }
  __syncthreads();
  s = red[0] + red[1] + red[2] + red[3];
  s2 = red[4] + red[5] + red[6] + red[7];
  float mean = s * (1.f / 1024.f);
  float var = s2 * (1.f / 1024.f) - mean * mean;
  float rstd = rsqrtf(var + 1e-5f);
  float4 gv = *(const float4*)(g + tid * 4);
  float4 bv = *(const float4*)(b + tid * 4);
  bf16x4 o;
  o[0] = (bf16)((vv.x - mean) * rstd * gv.x + bv.x);
  o[1] = (bf16)((vv.y - mean) * rstd * gv.y + bv.y);
  o[2] = (bf16)((vv.z - mean) * rstd * gv.z + bv.z);
  o[3] = (bf16)((vv.w - mean) * rstd * gv.w + bv.w);
  *(bf16x4*)(x1 + (size_t)row * 1024 + tid * 4) = o;
  if (row >= 2048) {
    bf16x4 xo;
    xo[0] = (bf16)vv.x; xo[1] = (bf16)vv.y; xo[2] = (bf16)vv.z; xo[3] = (bf16)vv.w;
    *(bf16x4*)(acat1x + (size_t)(row - 2048) * 2048 + tid * 4) = xo;
  }
}

// ------- K gather (contiguous per bh) + V transpose --------
__global__ __launch_bounds__(256) void kv_reorder(const bf16* kvb, bf16* Kc, bf16* vT) {
  int bh = blockIdx.y;
  int b = bh >> 4, h = bh & 15;
  int t0 = blockIdx.x * 64;
  int tid = threadIdx.x;
  {
    int t = t0 + (tid >> 2), d8 = (tid & 3) * 8;
    bf16x8 kk = *(const bf16x8*)(kvb + ((size_t)t * 4 + b) * 2048 + h * 64 + d8);
    *(bf16x8*)(Kc + ((size_t)bh * 1024 + t) * 64 + d8) = kk;
  }
  __shared__ bf16 tile[64][72];
  int tr = tid >> 4, tc = (tid & 15) * 4;
#pragma unroll
  for (int ph = 0; ph < 4; ph++) {
    int t = t0 + ph * 16 + tr;
    const bf16* src = kvb + ((size_t)t * 4 + b) * 2048 + 1024 + h * 64 + tc;
    bf16x4 vv = *(const bf16x4*)src;
    tile[tc + 0][ph * 16 + tr] = vv[0];
    tile[tc + 1][ph * 16 + tr] = vv[1];
    tile[tc + 2][ph * 16 + tr] = vv[2];
    tile[tc + 3][ph * 16 + tr] = vv[3];
  }
  __syncthreads();
#pragma unroll
  for (int ph = 0; ph < 4; ph++) {
    int d = ph * 16 + tr;
    bf16x4 o;
    o[0] = tile[d][tc + 0]; o[1] = tile[d][tc + 1]; o[2] = tile[d][tc + 2]; o[3] = tile[d][tc + 3];
    *(bf16x4*)(vT + ((size_t)bh * 64 + d) * 1024 + t0 + tc) = o;
  }
}

// ------- fused rel-pos flash attention: block-cooperative, GLD16 dbuf -------
__global__ __launch_bounds__(256, 2) void flash_attn(const bf16* qu, const bf16* Kc,
                                                     const bf16* vT, const bf16* Bsh,
                                                     bf16* av) {
  int qb = blockIdx.x;
  int bh = blockIdx.y;
  int b = bh >> 4, h = bh & 15;
  int tid = threadIdx.x;
  int wave = tid >> 6, lane = tid & 63;
  int g = lane >> 4, ln = lane & 15;
  int q0 = qb * 64;
  int qw = q0 + wave * 16;

  __shared__ bf16 Kb[2][64 * 64];
  __shared__ bf16 Vb[2][64 * 64];
  __shared__ bf16 Bb[2][64 * 64];
  __shared__ bf16 Pld[4][16 * 72];

  const bf16* qbase = qu + ((size_t)(qw + ln) * 4 + b) * 1024 + h * 64;
  bf16x8 aq0 = *(const bf16x8*)(qbase + g * 8);
  bf16x8 aq1 = *(const bf16x8*)(qbase + 32 + g * 8);

  int nk = qb + 9;

  auto issue = [&](int buf, int kt) {
    int k0 = kt * 64;
#pragma unroll
    for (int j = 0; j < 2; j++) {
      int i = tid + 256 * j;
      int r = i >> 3, c = (i & 7) ^ (r & 7);
      GLD16(&Kb[buf][i * 8], Kc + ((size_t)bh * 1024 + k0 + r) * 64 + c * 8);
    }
#pragma unroll
    for (int j = 0; j < 2; j++) {
      int i = tid + 256 * j;
      int r = i >> 3, c = (i & 7) ^ (r & 7);
      GLD16(&Vb[buf][i * 8], vT + ((size_t)bh * 64 + r) * 1024 + k0 + c * 8);
    }
#pragma unroll
    for (int j = 0; j < 2; j++) {
      int i = tid + 256 * j;
      int r = i >> 3, c = (i & 7) ^ (r & 7);
      GLD16(&Bb[buf][i * 8],
            Bsh + ((size_t)h * 2048 + (size_t)(q0 + r) * 4 + b) * 1024 + k0 + c * 8);
    }
  };

  f32x4 o[4] = {};
  float lp[4] = {0.f, 0.f, 0.f, 0.f};
  int qrow[4];
#pragma unroll
  for (int r = 0; r < 4; r++) qrow[r] = qw + g * 4 + r;

  issue(0, 0);
  for (int kt = 0; kt < nk; kt++) {
    __syncthreads();
    if (kt + 1 < nk) issue((kt + 1) & 1, kt + 1);
    const bf16* kb = Kb[kt & 1];
    const bf16* vb = Vb[kt & 1];
    const bf16* bb = Bb[kt & 1];
    int k0 = kt * 64;
#pragma unroll
    for (int s = 0; s < 4; s++) {
      int krow = s * 16 + ln;
      int sw = krow & 7;
      bf16x8 kb0 = *(const bf16x8*)(kb + krow * 64 + (g ^ sw) * 8);
      bf16x8 kb1 = *(const bf16x8*)(kb + krow * 64 + ((g + 4) ^ sw) * 8);
      f32x4 c = {0.f, 0.f, 0.f, 0.f};
      c = mfma16(aq0, kb0, c);
      c = mfma16(aq1, kb1, c);
      int k = k0 + s * 16 + ln;
#pragma unroll
      for (int r = 0; r < 4; r++) {
        int qr = wave * 16 + g * 4 + r;
        int col = s * 16 + ln;
        int ch = (col >> 3) ^ (qr & 7);
        float pb = (float)bb[qr * 64 + ch * 8 + (col & 7)];
        float P = (k <= qrow[r] + 512) ? __expf((c[r] + pb) * 0.125f) : 0.f;
        lp[r] += P;
        Pld[wave][(g * 4 + r) * 72 + s * 16 + ln] = (bf16)P;
      }
    }
    bf16x8 pa0 = *(const bf16x8*)&Pld[wave][ln * 72 + g * 8];
    bf16x8 pa1 = *(const bf16x8*)&Pld[wave][ln * 72 + 32 + g * 8];
#pragma unroll
    for (int ni = 0; ni < 4; ni++) {
      int drow = ni * 16 + ln;
      int sw = drow & 7;
      bf16x8 v0 = *(const bf16x8*)(vb + drow * 64 + (g ^ sw) * 8);
      bf16x8 v1 = *(const bf16x8*)(vb + drow * 64 + ((g + 4) ^ sw) * 8);
      o[ni] = mfma16(pa0, v0, o[ni]);
      o[ni] = mfma16(pa1, v1, o[ni]);
    }
  }
#pragma unroll
  for (int off = 1; off < 16; off <<= 1)
#pragma unroll
    for (int r = 0; r < 4; r++) lp[r] += __shfl_xor(lp[r], off, 64);
#pragma unroll
  for (int r = 0; r < 4; r++) {
    float inv = 1.f / lp[r];
    bf16* dst = av + ((size_t)qrow[r] * 4 + b) * 1024 + h * 64;
#pragma unroll
    for (int ni = 0; ni < 4; ni++) dst[ni * 16 + ln] = (bf16)(o[ni][r] * inv);
  }
}

// ---------------- elementwise ----------------
__global__ void rx_kernel(const float* r, const float* x, bf16* dst, int n) {
  int i = (blockIdx.x * 256 + threadIdx.x) * 4;
  if (i >= n) return;
  float4 rv = *(const float4*)(r + i);
  float4 xv = *(const float4*)(x + i);
  int row = i >> 10, c = i & 1023;
  bf16x4 o;
  o[0] = (bf16)(rv.x * xv.x); o[1] = (bf16)(rv.y * xv.y);
  o[2] = (bf16)(rv.z * xv.z); o[3] = (bf16)(rv.w * xv.w);
  *(bf16x4*)(dst + (size_t)row * 2048 + c) = o;
}

__global__ __launch_bounds__(256) void gru_combine_ln(const float* z, const float* h, const float* x,
                                                      const float* g, const float* b,
                                                      float* o1, bf16* x2, bf16* o1b) {
  int row = blockIdx.x, tid = threadIdx.x;
  size_t base = (size_t)row * 1024 + tid * 4;
  float4 zv = *(const float4*)(z + base);
  float4 hv = *(const float4*)(h + base);
  float4 xv = *(const float4*)(x + base);
  float4 ov;
  ov.x = (1.f - zv.x) * xv.x + zv.x * hv.x;
  ov.y = (1.f - zv.y) * xv.y + zv.y * hv.y;
  ov.z = (1.f - zv.z) * xv.z + zv.z * hv.z;
  ov.w = (1.f - zv.w) * xv.w + zv.w * hv.w;
  *(float4*)(o1 + base) = ov;
  bf16x4 ob; ob[0] = (bf16)ov.x; ob[1] = (bf16)ov.y; ob[2] = (bf16)ov.z; ob[3] = (bf16)ov.w;
  *(bf16x4*)(o1b + (size_t)row * 2048 + tid * 4) = ob;
  float s = ov.x + ov.y + ov.z + ov.w;
  float s2 = ov.x * ov.x + ov.y * ov.y + ov.z * ov.z + ov.w * ov.w;
#pragma unroll
  for (int off = 1; off < 64; off <<= 1) { s += __shfl_xor(s, off, 64); s2 += __shfl_xor(s2, off, 64); }
  __shared__ float red[8];
  int wave = tid >> 6, lane = tid & 63;
  if (lane == 0) { red[wave] = s; red[4 + wave] = s2; }
  __syncthreads();
  s = red[0] + red[1] + red[2] + red[3];
  s2 = red[4] + red[5] + red[6] + red[7];
  float mean = s * (1.f / 1024.f);
  float var = s2 * (1.f / 1024.f) - mean * mean;
  float rstd = rsqrtf(var + 1e-5f);
  float4 gv = *(const float4*)(g + tid * 4);
  float4 bv = *(const float4*)(b + tid * 4);
  bf16x4 xo;
  xo[0] = (bf16)((ov.x - mean) * rstd * gv.x + bv.x);
  xo[1] = (bf16)((ov.y - mean) * rstd * gv.y + bv.y);
  xo[2] = (bf16)((ov.z - mean) * rstd * gv.z + bv.z);
  xo[3] = (bf16)((ov.w - mean) * rstd * gv.w + bv.w);
  *(bf16x4*)(x2 + base) = xo;
}

__global__ void final_combine(const float* z, const float* h, const float* o1, float* out, int n) {
  int i = (blockIdx.x * 256 + threadIdx.x) * 4;
  if (i >= n) return;
  float4 zv = *(const float4*)(z + i);
  float4 hv = *(const float4*)(h + i);
  float4 xv = *(const float4*)(o1 + i);
  float4 o;
  o.x = (1.f - zv.x) * xv.x + zv.x * hv.x;
  o.y = (1.f - zv.y) * xv.y + zv.y * hv.y;
  o.z = (1.f - zv.z) * xv.z + zv.z * hv.z;
  o.w = (1.f - zv.w) * xv.w + zv.w * hv.w;
  *(float4*)(out + i) = o;
}

// ---------------- host ----------------
extern "C" void kernel_launch(void* const* d_in, const int* in_sizes, int n_in,
                              void* d_out, int out_size, void* d_ws, size_t ws_size,
                              hipStream_t stream) {
  (void)in_sizes; (void)n_in; (void)out_size; (void)ws_size;
  const float* inputs  = (const float*)d_in[0];
  const float* memory  = (const float*)d_in[1];
  const float* pos_emb = (const float*)d_in[2];
  const float* u_in    = (const float*)d_in[3];
  const float* v_in    = (const float*)d_in[4];
  const float* W_kv    = (const float*)d_in[5];
  const float* b_kv    = (const float*)d_in[6];
  const float* W_q     = (const float*)d_in[7];
  const float* b_q     = (const float*)d_in[8];
  const float* W_proj  = (const float*)d_in[9];
  const float* b_proj  = (const float*)d_in[10];
  const float* W_pos   = (const float*)d_in[11];
  const float* b_pos   = (const float*)d_in[12];
  const float* ln1_g   = (const float*)d_in[13];
  const float* ln1_b   = (const float*)d_in[14];
  const float* ln2_g   = (const float*)d_in[15];
  const float* ln2_b   = (const float*)d_in[16];
  const float* Wr1 = (const float*)d_in[17];
  const float* Ur1 = (const float*)d_in[18];
  const float* Wz1 = (const float*)d_in[19];
  const float* Uz1 = (const float*)d_in[20];
  const float* Wg1 = (const float*)d_in[21];
  const float* Ug1 = (const float*)d_in[22];
  const float* bg1 = (const float*)d_in[23];
  const float* Wr2 = (const float*)d_in[24];
  const float* Ur2 = (const float*)d_in[25];
  const float* Wz2 = (const float*)d_in[26];
  const float* Uz2 = (const float*)d_in[27];
  const float* Wg2 = (const float*)d_in[28];
  const float* Ug2 = (const float*)d_in[29];
  const float* bg2 = (const float*)d_in[30];
  const float* W1  = (const float*)d_in[31];
  const float* b1  = (const float*)d_in[32];
  const float* W2  = (const float*)d_in[33];
  const float* b2  = (const float*)d_in[34];

  char* ws = (char*)d_ws;
  size_t off = 0;
  auto alloc = [&](size_t bytes) -> char* {
    char* p = ws + off;
    off += (bytes + 255) & ~(size_t)255;
    return p;
  };
  bf16* x1      = (bf16*)alloc(4096ull * 1024 * 2);
  bf16* Wkv_t   = (bf16*)alloc(2048ull * 1024 * 2);
  bf16* Wq_t    = (bf16*)alloc(1024ull * 1024 * 2);
  bf16* Wpos_t  = (bf16*)alloc(1024ull * 1024 * 2);
  bf16* Wproj_t = (bf16*)alloc(1024ull * 1024 * 2);
  bf16* Bzr1    = (bf16*)alloc(2048ull * 2048 * 2);
  bf16* Bg1     = (bf16*)alloc(1024ull * 2048 * 2);
  bf16* Bzr2    = (bf16*)alloc(2048ull * 2048 * 2);
  bf16* Bg2     = (bf16*)alloc(1024ull * 2048 * 2);
  bf16* W1t     = (bf16*)alloc(4096ull * 1024 * 2);
  bf16* W2t     = (bf16*)alloc(1024ull * 4096 * 2);
  bf16* posb    = (bf16*)alloc(1024ull * 1024 * 2);
  bf16* kvb     = (bf16*)alloc(4096ull * 2048 * 2);
  bf16* qu      = (bf16*)alloc(2048ull * 1024 * 2);
  bf16* qv      = (bf16*)alloc(2048ull * 1024 * 2);
  bf16* rb      = (bf16*)alloc(1024ull * 1024 * 2);
  bf16* Kc      = (bf16*)alloc(64ull * 1024 * 64 * 2);
  bf16* vT      = (bf16*)alloc(64ull * 64 * 1024 * 2);
  bf16* av      = (bf16*)alloc(2048ull * 1024 * 2);
  bf16* acat1   = (bf16*)alloc(2048ull * 2048 * 2);
  bf16* acat2   = (bf16*)alloc(2048ull * 2048 * 2);
  bf16* x2      = (bf16*)alloc(2048ull * 1024 * 2);
  char* arena   = alloc(64ull << 20);
  bf16*  Bshift = (bf16*)arena;                  // [h][q*4+b][k] pre-shifted
  float* zf   = (float*)arena;                   // [0,8M)
  float* rf   = (float*)(arena + (8ull << 20));  // [8,16M)
  float* hf   = (float*)(arena + (16ull << 20)); // [16,24M)
  float* o1   = (float*)(arena + (24ull << 20)); // [24,32M)
  bf16*  tffn = (bf16*)(arena + (32ull << 20));  // [32,48M)
  float* part = (float*)(arena + (48ull << 20)); // [48,64M): 2x 2048x1024 f32

  TPack tp;
  int di = 0;
  auto setd = [&](const float* s, bf16* d, int K, int N, int ldd) {
    tp.d[di].src = s; tp.d[di].dst = d; tp.d[di].K = K; tp.d[di].N = N; tp.d[di].ldd = ldd; di++;
  };
  setd(W_kv, Wkv_t, 1024, 2048, 1024);
  setd(W_q, Wq_t, 1024, 1024, 1024);
  setd(W_pos, Wpos_t, 1024, 1024, 1024);
  setd(W_proj, Wproj_t, 1024, 1024, 1024);
  setd(Wz1, Bzr1, 1024, 1024, 2048);              setd(Uz1, Bzr1 + 1024, 1024, 1024, 2048);
  setd(Wr1, Bzr1 + 1024ull * 2048, 1024, 1024, 2048); setd(Ur1, Bzr1 + 1024ull * 2048 + 1024, 1024, 1024, 2048);
  setd(Wg1, Bg1, 1024, 1024, 2048);               setd(Ug1, Bg1 + 1024, 1024, 1024, 2048);
  setd(Wz2, Bzr2, 1024, 1024, 2048);              setd(Uz2, Bzr2 + 1024, 1024, 1024, 2048);
  setd(Wr2, Bzr2 + 1024ull * 2048, 1024, 1024, 2048); setd(Ur2, Bzr2 + 1024ull * 2048 + 1024, 1024, 1024, 2048);
  setd(Wg2, Bg2, 1024, 1024, 2048);               setd(Ug2, Bg2 + 1024, 1024, 1024, 2048);
  setd(W1, W1t, 1024, 4096, 1024);
  setd(W2, W2t, 4096, 1024, 4096);
  wt_transpose<<<dim3(1024, 1, 18), 256, 0, stream>>>(tp);
  convertf2b<<<1024, 256, 0, stream>>>(pos_emb, posb, 1024 * 1024);
  ln1_kernel<<<4096, 256, 0, stream>>>(inputs, memory, ln1_g, ln1_b, x1, acat1 + 1024);

  auto gemm = [&](const bf16* A, int lda, const bf16* B, int ldb,
                  bf16* Cb, bf16* Cb2, float* Cf, float* Cf2, int ldc,
                  int M, int N, int K, const float* bias, int mode,
                  int bat, int S, long long Ab, long long Bb, long long Cbt,
                  const float* up, const float* vp) {
    GemmP p;
    p.A = A; p.B = B; p.Cb = Cb; p.Cb2 = Cb2; p.Cf = Cf; p.Cf2 = Cf2;
    p.bias = bias; p.up = up; p.vp = vp;
    p.K = K; p.lda = lda; p.ldb = ldb; p.ldc = ldc;
    p.Abat = Ab; p.Bbat = Bb; p.Cbat = Cbt; p.mode = mode;
    p.S = S; p.Ksl = K / S;
    if (mode == M_SHIFT)
      gemm_v4<64, 64, 128><<<dim3(M / 64, N / 64, bat * S), 128, 0, stream>>>(p);
    else
      gemm_v5<<<dim3(M / 128, N / 64, bat * S), 256, 0, stream>>>(p);
  };

  // projections
  gemm(x1, 1024, Wkv_t, 1024, kvb, nullptr, nullptr, nullptr, 2048, 4096, 2048, 1024, b_kv, M_BF16, 1, 1, 0, 0, 0, nullptr, nullptr);
  gemm(x1 + 2048ull * 1024, 1024, Wq_t, 1024, qu, qv, nullptr, nullptr, 1024, 2048, 1024, 1024, b_q, M_QUV, 1, 1, 0, 0, 0, u_in, v_in);
  gemm(posb, 1024, Wpos_t, 1024, rb, nullptr, nullptr, nullptr, 1024, 1024, 1024, 1024, b_pos, M_BF16, 1, 1, 0, 0, 0, nullptr, nullptr);
  kv_reorder<<<dim3(16, 64), 256, 0, stream>>>(kvb, Kc, vT);
  // Bshift[h][m][k] = (qv_h @ r_h^T) rel-shifted in vectorized epilogue
  gemm(qv, 1024, rb, 1024, Bshift, nullptr, nullptr, nullptr, 1024, 2048, 1024, 64, nullptr, M_SHIFT, 16, 1, 64, 64, 2048ll * 1024, nullptr, nullptr);
  flash_attn<<<dim3(8, 64), 256, 0, stream>>>(qu, Kc, vT, Bshift, av);
  // a1 = relu(av @ Wproj + b) into Acat1 cols [0,1024)
  gemm(av, 1024, Wproj_t, 1024, acat1, nullptr, nullptr, nullptr, 2048, 2048, 1024, 1024, b_proj, M_BF16_RELU, 1, 1, 0, 0, 0, nullptr, nullptr);
  // GRU1: z|r fused
  gemm(acat1, 2048, Bzr1, 2048, nullptr, nullptr, zf, rf, 1024, 2048, 2048, 2048, bg1, M_ZR, 1, 1, 0, 0, 0, nullptr, nullptr);
  rx_kernel<<<2048, 256, 0, stream>>>(rf, inputs, acat1 + 1024, 2048 * 1024);
  gemm(acat1, 2048, Bg1, 2048, nullptr, nullptr, part, nullptr, 1024, 2048, 1024, 2048, nullptr, M_F32, 1, 2, 0, 0, 2048ll * 1024, nullptr, nullptr);
  reduce2<<<2048, 256, 0, stream>>>(part, part + 2048ull * 1024, nullptr, nullptr, hf, 1024, M_TANH, 2048 * 1024);
  gru_combine_ln<<<2048, 256, 0, stream>>>(zf, hf, inputs, ln2_g, ln2_b, o1, x2, acat2 + 1024);
  // FFN
  gemm(x2, 1024, W1t, 1024, tffn, nullptr, nullptr, nullptr, 4096, 2048, 4096, 1024, b1, M_BF16_RELU, 1, 1, 0, 0, 0, nullptr, nullptr);
  gemm(tffn, 4096, W2t, 4096, nullptr, nullptr, part, nullptr, 1024, 2048, 1024, 4096, nullptr, M_F32, 1, 2, 0, 0, 2048ll * 1024, nullptr, nullptr);
  reduce2<<<2048, 256, 0, stream>>>(part, part + 2048ull * 1024, b2, acat2, nullptr, 2048, M_BF16_RELU, 2048 * 1024);
  // GRU2
  gemm(acat2, 2048, Bzr2, 2048, nullptr, nullptr, zf, rf, 1024, 2048, 2048, 2048, bg2, M_ZR, 1, 1, 0, 0, 0, nullptr, nullptr);
  rx_kernel<<<2048, 256, 0, stream>>>(rf, o1, acat2 + 1024, 2048 * 1024);
  gemm(acat2, 2048, Bg2, 2048, nullptr, nullptr, part, nullptr, 1024, 2048, 1024, 2048, nullptr, M_F32, 1, 2, 0, 0, 2048ll * 1024, nullptr, nullptr);
  reduce2<<<2048, 256, 0, stream>>>(part, part + 2048ull * 1024, nullptr, nullptr, hf, 1024, M_TANH, 2048 * 1024);
  final_combine<<<2048, 256, 0, stream>>>(zf, hf, o1, (float*)d_out, 2048 * 1024);
}

// Round 8
// 606.223 us; speedup vs baseline: 1.6681x; 1.6681x over previous
//
#include <hip/hip_runtime.h>
#include <math.h>

typedef __bf16 bf16;
typedef __bf16 bf16x8 __attribute__((ext_vector_type(8)));
typedef __bf16 bf16x4 __attribute__((ext_vector_type(4)));
typedef __bf16 bf16x2 __attribute__((ext_vector_type(2)));
typedef float f32x4 __attribute__((ext_vector_type(4)));

__device__ __forceinline__ float sigmoid_(float x) { return 1.f / (1.f + __expf(-x)); }
__device__ __forceinline__ f32x4 mfma16(bf16x8 a, bf16x8 b, f32x4 c) {
  return __builtin_amdgcn_mfma_f32_16x16x32_bf16(a, b, c, 0, 0, 0);
}

// async global->LDS, 16B per lane. LDS dest must be wave-uniform base + lane*16.
#define GLD16(ldsp, gp)                                                        \
  __builtin_amdgcn_global_load_lds(                                            \
      (__attribute__((address_space(1))) void*)(gp),                           \
      (__attribute__((address_space(3))) void*)(ldsp), 16, 0, 0)

enum { M_F32 = 0, M_BF16 = 1, M_BF16_RELU = 2, M_SIG = 3, M_SIG_NEG = 4,
       M_TANH = 5, M_QUV = 6, M_ZR = 7, M_SHIFT = 8, M_ZRX = 9 };

struct GemmP {
  const bf16* A; const bf16* A2; const bf16* B;
  bf16* Cb; bf16* Cb2; float* Cf; float* Cf2;
  const float* bias; const float* up; const float* vp;
  int K, lda, lda2, ldb, ldc;
  long long Abat, Bbat, Cbat;
  int mode, S, Ksl;
};

__device__ __forceinline__ void epilogue_store(const GemmP& p, long long cb, bool part,
                                               int row, int col, float a) {
  long long ro = cb + (long long)row * p.ldc;
  if (part) { p.Cf[ro + col] = a; return; }
  float bv = p.bias ? p.bias[col] : 0.f;
  switch (p.mode) {
    case M_F32: p.Cf[ro + col] = a + bv; break;
    case M_BF16: p.Cb[ro + col] = (bf16)(a + bv); break;
    case M_BF16_RELU: { float t = a + bv; p.Cb[ro + col] = (bf16)(t > 0.f ? t : 0.f); } break;
    case M_SIG: p.Cf[ro + col] = sigmoid_(a + bv); break;
    case M_TANH: p.Cf[ro + col] = tanhf(a + bv); break;
    case M_QUV: {
      float t = a + bv;
      p.Cb[ro + col] = (bf16)(t + p.up[col]);
      p.Cb2[ro + col] = (bf16)(t + p.vp[col]);
    } break;
    case M_ZR: {
      if (col < 1024) p.Cf[(long long)row * 1024 + col] = sigmoid_(a - p.bias[col]);
      else p.Cf2[(long long)row * 1024 + col - 1024] = sigmoid_(a);
    } break;
    case M_ZRX: {  // z -> Cf ; r*x -> Cb (rxbuf, 1024-wide), x fp32 in p.up
      if (col < 1024) p.Cf[(long long)row * 1024 + col] = sigmoid_(a - p.bias[col]);
      else {
        int c2 = col - 1024;
        long long xo = (long long)row * 1024 + c2;
        p.Cb[xo] = (bf16)(sigmoid_(a) * p.up[xo]);
      }
    } break;
    default: break;
  }
}

// ---- GEMM v6: 128x64 tile, BK=128, single-buffered GLD16, XOR-16 swizzle ---
// B in (N,K). 4 waves, wave = 32x64. Ksl must be a multiple of 128.
// Split-K slice 1 may use a separate A matrix (p.A2/lda2) for fused GRU-g.
__global__ __launch_bounds__(256, 3) void gemm_v6(GemmP p) {
  __shared__ bf16 As[128 * 128];  // 32 KB
  __shared__ bf16 Bs[64 * 128];   // 16 KB
  const int tid = threadIdx.x;
  const int wave = tid >> 6, lane = tid & 63;
  const int g = lane >> 4, ln = lane & 15;
  const int bz = blockIdx.z;
  const int batch = bz / p.S, slice = bz % p.S;
  const bf16* A; int lda;
  if (slice == 1 && p.A2) { A = p.A2; lda = p.lda2; }
  else { A = p.A + (long long)batch * p.Abat + (long long)slice * p.Ksl; lda = p.lda; }
  const bf16* B = p.B + (long long)batch * p.Bbat + (long long)slice * p.Ksl;
  const int m0 = blockIdx.x * 128, n0 = blockIdx.y * 64;
  const int niters = p.Ksl >> 7;

  f32x4 acc[2][4] = {};
  for (int it = 0; it < niters; it++) {
    const int k0 = it << 7;
    __syncthreads();  // previous tile's LDS reads complete
#pragma unroll
    for (int j = 0; j < 8; j++) {
      int i = tid + 256 * j;
      int r = i >> 4, c = (i & 15) ^ (r & 15);
      GLD16(As + i * 8, A + (long long)(m0 + r) * lda + k0 + c * 8);
    }
#pragma unroll
    for (int j = 0; j < 4; j++) {
      int i = tid + 256 * j;
      int r = i >> 4, c = (i & 15) ^ (r & 15);
      GLD16(Bs + i * 8, B + (long long)(n0 + r) * p.ldb + k0 + c * 8);
    }
    __syncthreads();  // drain staging
#pragma unroll
    for (int kh = 0; kh < 4; kh++) {
      bf16x8 af[2], bfm[4];
#pragma unroll
      for (int mi = 0; mi < 2; mi++) {
        int row = wave * 32 + mi * 16 + ln;
        int slot = (kh * 4 + g) ^ (row & 15);
        af[mi] = *(const bf16x8*)(As + row * 128 + slot * 8);
      }
#pragma unroll
      for (int ni = 0; ni < 4; ni++) {
        int row = ni * 16 + ln;
        int slot = (kh * 4 + g) ^ (row & 15);
        bfm[ni] = *(const bf16x8*)(Bs + row * 128 + slot * 8);
      }
#pragma unroll
      for (int mi = 0; mi < 2; mi++)
#pragma unroll
        for (int ni = 0; ni < 4; ni++)
          acc[mi][ni] = mfma16(af[mi], bfm[ni], acc[mi][ni]);
    }
  }

  const long long cb = (long long)bz * p.Cbat;
  const bool part = (p.S > 1) && (p.mode == M_F32);
#pragma unroll
  for (int mi = 0; mi < 2; mi++)
#pragma unroll
    for (int r = 0; r < 4; r++) {
      int row = m0 + wave * 32 + mi * 16 + g * 4 + r;
#pragma unroll
      for (int ni = 0; ni < 4; ni++)
        epilogue_store(p, cb, part, row, n0 + ni * 16 + ln, acc[mi][ni][r]);
    }
}

// ---------------- GEMM v4 (M_SHIFT / K=64 path): BK=64, GLD16 dbuf ---------
template <int BM, int BN, int T>
__global__ __launch_bounds__(T, 2) void gemm_v4(GemmP p) {
  constexpr int AISS = BM * 8 / T;
  constexpr int BISS = BN * 8 / T;
  constexpr int NW = T / 64;
  constexpr int WCOLS = (BN == 128) ? 2 : 1;
  constexpr int WROWS = NW / WCOLS;
  constexpr int MI = BM / (WROWS * 16);
  __shared__ bf16 smem[2 * (BM + BN) * 64];
  bf16* Asm = smem;
  bf16* Bsm = smem + 2 * BM * 64;
  const int tid = threadIdx.x;
  const int wave = tid >> 6, lane = tid & 63;
  const int g = lane >> 4, ln = lane & 15;
  const int wr = wave / WCOLS;
  const int wc = wave % WCOLS;
  const int bz = blockIdx.z;
  const int batch = bz / p.S, slice = bz % p.S;
  const bf16* A = p.A + (long long)batch * p.Abat + (long long)slice * p.Ksl;
  const bf16* B = p.B + (long long)batch * p.Bbat + (long long)slice * p.Ksl;
  const int m0 = blockIdx.x * BM, n0 = blockIdx.y * BN;
  const int niters = p.Ksl >> 6;

  auto issue = [&](int buf, int k0) {
#pragma unroll
    for (int j = 0; j < AISS; j++) {
      int i = tid + T * j;
      int r = i >> 3, c = (i & 7) ^ (r & 7);
      GLD16(Asm + buf * BM * 64 + i * 8, A + (long long)(m0 + r) * p.lda + k0 + c * 8);
    }
#pragma unroll
    for (int j = 0; j < BISS; j++) {
      int i = tid + T * j;
      int r = i >> 3, c = (i & 7) ^ (r & 7);
      GLD16(Bsm + buf * BN * 64 + i * 8, B + (long long)(n0 + r) * p.ldb + k0 + c * 8);
    }
  };

  f32x4 acc[MI][4] = {};
  issue(0, 0);
  __syncthreads();
  for (int it = 0; it < niters; it++) {
    if (it + 1 < niters) issue((it + 1) & 1, (it + 1) << 6);
    const bf16* as = Asm + (it & 1) * BM * 64;
    const bf16* bs = Bsm + (it & 1) * BN * 64;
    bf16x8 af[MI][2], bfm[4][2];
#pragma unroll
    for (int mi = 0; mi < MI; mi++) {
      int row = wr * (16 * MI) + mi * 16 + ln;
#pragma unroll
      for (int kh = 0; kh < 2; kh++) {
        int ch = (kh * 4 + g) ^ (row & 7);
        af[mi][kh] = *(const bf16x8*)(as + row * 64 + ch * 8);
      }
    }
#pragma unroll
    for (int ni = 0; ni < 4; ni++) {
      int row = wc * 64 + ni * 16 + ln;
#pragma unroll
      for (int kh = 0; kh < 2; kh++) {
        int ch = (kh * 4 + g) ^ (row & 7);
        bfm[ni][kh] = *(const bf16x8*)(bs + row * 64 + ch * 8);
      }
    }
#pragma unroll
    for (int kh = 0; kh < 2; kh++)
#pragma unroll
      for (int mi = 0; mi < MI; mi++)
#pragma unroll
        for (int ni = 0; ni < 4; ni++)
          acc[mi][ni] = mfma16(af[mi][kh], bfm[ni][kh], acc[mi][ni]);
    __syncthreads();
  }

  const long long cb = (long long)bz * p.Cbat;

  if constexpr (BM == 64 && BN == 64) {
    if (p.mode == M_SHIFT) {
      float* Ct = (float*)smem;  // 64 x 65 f32
#pragma unroll
      for (int mi = 0; mi < MI; mi++)
#pragma unroll
        for (int r = 0; r < 4; r++) {
          int row = wave * 32 + mi * 16 + g * 4 + r;
#pragma unroll
          for (int ni = 0; ni < 4; ni++)
            Ct[row * 65 + ni * 16 + ln] = acc[mi][ni][r];
        }
      __syncthreads();
      int row = tid & 63;
      int c0 = (tid >> 6) * 32;
      int m = m0 + row;
      int q = m >> 2;
      long long ro = cb + (long long)m * p.ldc;
      bf16* dst = p.Cb + ro;
      const float* src = Ct + row * 65 + c0;
      int kstart = n0 + c0 - 511 + q;
      int idx = (kstart < 0) ? -kstart : 0;
      if (idx < 32) {
        int k = kstart + idx;
        if (k & 1) { dst[k] = (bf16)src[idx]; idx++; k++; }
        if ((k & 2) && idx + 1 < 32) {
          bf16x2 o; o[0] = (bf16)src[idx]; o[1] = (bf16)src[idx + 1];
          *(bf16x2*)(dst + k) = o; idx += 2; k += 2;
        }
        for (; idx + 3 < 32; idx += 4, k += 4) {
          bf16x4 o;
          o[0] = (bf16)src[idx];     o[1] = (bf16)src[idx + 1];
          o[2] = (bf16)src[idx + 2]; o[3] = (bf16)src[idx + 3];
          *(bf16x4*)(dst + k) = o;
        }
        if (idx + 1 < 32) {
          bf16x2 o; o[0] = (bf16)src[idx]; o[1] = (bf16)src[idx + 1];
          *(bf16x2*)(dst + k) = o; idx += 2; k += 2;
        }
        if (idx < 32) dst[k] = (bf16)src[idx];
      }
      return;
    }
  }

  const bool part = (p.S > 1) && (p.mode == M_F32);
#pragma unroll
  for (int mi = 0; mi < MI; mi++)
#pragma unroll
    for (int r = 0; r < 4; r++) {
      int row = m0 + wr * (16 * MI) + mi * 16 + g * 4 + r;
#pragma unroll
      for (int ni = 0; ni < 4; ni++)
        epilogue_store(p, cb, part, row, n0 + wc * 64 + ni * 16 + ln, acc[mi][ni][r]);
    }
}

// split-K=2 partial reduce + bias + relu -> bf16 (used for FFN2)
__global__ void reduce2(const float* p0, const float* p1, const float* bias,
                        bf16* ob, int ldc, int n) {
  int i = (blockIdx.x * 256 + threadIdx.x) * 4;
  if (i >= n) return;
  float4 a = *(const float4*)(p0 + i);
  float4 b = *(const float4*)(p1 + i);
  int row = i >> 10, col = i & 1023;
  float v0 = a.x + b.x + bias[col], v1 = a.y + b.y + bias[col + 1];
  float v2 = a.z + b.z + bias[col + 2], v3 = a.w + b.w + bias[col + 3];
  bf16x4 o;
  o[0] = (bf16)(v0 > 0.f ? v0 : 0.f); o[1] = (bf16)(v1 > 0.f ? v1 : 0.f);
  o[2] = (bf16)(v2 > 0.f ? v2 : 0.f); o[3] = (bf16)(v3 > 0.f ? v3 : 0.f);
  *(bf16x4*)(ob + (size_t)row * ldc + col) = o;
}

// ---------------- weight transpose + fp32->bf16 convert ----------------
struct TDesc { const float* src; bf16* dst; int K, N, ldd; };
struct TPack { TDesc d[18]; };

__global__ __launch_bounds__(256) void wt_transpose(TPack tp) {
  TDesc t = tp.d[blockIdx.z];
  int ntx = t.N >> 6, nty = t.K >> 6;
  int tile = blockIdx.x;
  if (tile >= ntx * nty) return;
  int k0 = (tile / ntx) * 64, n0 = (tile % ntx) * 64;
  __shared__ bf16 tb[64][72];
  int tid = threadIdx.x;
  int tr = tid >> 4, tc = (tid & 15) * 4;
#pragma unroll
  for (int ph = 0; ph < 4; ph++) {
    int k = k0 + ph * 16 + tr;
    float4 vv = *(const float4*)(t.src + (size_t)k * t.N + n0 + tc);
    tb[tc + 0][ph * 16 + tr] = (bf16)vv.x;
    tb[tc + 1][ph * 16 + tr] = (bf16)vv.y;
    tb[tc + 2][ph * 16 + tr] = (bf16)vv.z;
    tb[tc + 3][ph * 16 + tr] = (bf16)vv.w;
  }
  __syncthreads();
#pragma unroll
  for (int ph = 0; ph < 4; ph++) {
    int n = ph * 16 + tr;
    bf16x4 o;
    o[0] = tb[n][tc + 0]; o[1] = tb[n][tc + 1]; o[2] = tb[n][tc + 2]; o[3] = tb[n][tc + 3];
    *(bf16x4*)(t.dst + (size_t)(n0 + n) * t.ldd + k0 + tc) = o;
  }
}

__global__ void convertf2b(const float* src, bf16* dst, int n) {
  int i = (blockIdx.x * 256 + threadIdx.x) * 4;
  if (i >= n) return;
  float4 vv = *(const float4*)(src + i);
  bf16x4 o; o[0] = (bf16)vv.x; o[1] = (bf16)vv.y; o[2] = (bf16)vv.z; o[3] = (bf16)vv.w;
  *(bf16x4*)(dst + i) = o;
}

// ---------------- LayerNorm 1 (concat(memory, inputs)) ----------------
__global__ __launch_bounds__(256) void ln1_kernel(const float* inputs, const float* memory,
                                                  const float* g, const float* b,
                                                  bf16* x1, bf16* acat1x) {
  int row = blockIdx.x;
  int tid = threadIdx.x;
  const float* src = (row < 2048) ? (memory + (size_t)row * 1024)
                                  : (inputs + (size_t)(row - 2048) * 1024);
  float4 vv = *(const float4*)(src + tid * 4);
  float s = vv.x + vv.y + vv.z + vv.w;
  float s2 = vv.x * vv.x + vv.y * vv.y + vv.z * vv.z + vv.w * vv.w;
#pragma unroll
  for (int off = 1; off < 64; off <<= 1) { s += __shfl_xor(s, off, 64); s2 += __shfl_xor(s2, off, 64); }
  __shared__ float red[8];
  int wave = tid >> 6, lane = tid & 63;
  if (lane == 0) { red[wave] = s; red[4 + wave] = s2; }
  __syncthreads();
  s = red[0] + red[1] + red[2] + red[3];
  s2 = red[4] + red[5] + red[6] + red[7];
  float mean = s * (1.f / 1024.f);
  float var = s2 * (1.f / 1024.f) - mean * mean;
  float rstd = rsqrtf(var + 1e-5f);
  float4 gv = *(const float4*)(g + tid * 4);
  float4 bv = *(const float4*)(b + tid * 4);
  bf16x4 o;
  o[0] = (bf16)((vv.x - mean) * rstd * gv.x + bv.x);
  o[1] = (bf16)((vv.y - mean) * rstd * gv.y + bv.y);
  o[2] = (bf16)((vv.z - mean) * rstd * gv.z + bv.z);
  o[3] = (bf16)((vv.w - mean) * rstd * gv.w + bv.w);
  *(bf16x4*)(x1 + (size_t)row * 1024 + tid * 4) = o;
  if (row >= 2048) {
    bf16x4 xo;
    xo[0] = (bf16)vv.x; xo[1] = (bf16)vv.y; xo[2] = (bf16)vv.z; xo[3] = (bf16)vv.w;
    *(bf16x4*)(acat1x + (size_t)(row - 2048) * 2048 + tid * 4) = xo;
  }
}

// ------- K gather (contiguous per bh) + V transpose --------
__global__ __launch_bounds__(256) void kv_reorder(const bf16* kvb, bf16* Kc, bf16* vT) {
  int bh = blockIdx.y;
  int b = bh >> 4, h = bh & 15;
  int t0 = blockIdx.x * 64;
  int tid = threadIdx.x;
  {
    int t = t0 + (tid >> 2), d8 = (tid & 3) * 8;
    bf16x8 kk = *(const bf16x8*)(kvb + ((size_t)t * 4 + b) * 2048 + h * 64 + d8);
    *(bf16x8*)(Kc + ((size_t)bh * 1024 + t) * 64 + d8) = kk;
  }
  __shared__ bf16 tile[64][72];
  int tr = tid >> 4, tc = (tid & 15) * 4;
#pragma unroll
  for (int ph = 0; ph < 4; ph++) {
    int t = t0 + ph * 16 + tr;
    const bf16* src = kvb + ((size_t)t * 4 + b) * 2048 + 1024 + h * 64 + tc;
    bf16x4 vv = *(const bf16x4*)src;
    tile[tc + 0][ph * 16 + tr] = vv[0];
    tile[tc + 1][ph * 16 + tr] = vv[1];
    tile[tc + 2][ph * 16 + tr] = vv[2];
    tile[tc + 3][ph * 16 + tr] = vv[3];
  }
  __syncthreads();
#pragma unroll
  for (int ph = 0; ph < 4; ph++) {
    int d = ph * 16 + tr;
    bf16x4 o;
    o[0] = tile[d][tc + 0]; o[1] = tile[d][tc + 1]; o[2] = tile[d][tc + 2]; o[3] = tile[d][tc + 3];
    *(bf16x4*)(vT + ((size_t)bh * 64 + d) * 1024 + t0 + tc) = o;
  }
}

// ------- fused rel-pos flash attention: block-cooperative, GLD16 dbuf -------
__global__ __launch_bounds__(256, 2) void flash_attn(const bf16* qu, const bf16* Kc,
                                                     const bf16* vT, const bf16* Bsh,
                                                     bf16* av) {
  int qb = blockIdx.x;
  int bh = blockIdx.y;
  int b = bh >> 4, h = bh & 15;
  int tid = threadIdx.x;
  int wave = tid >> 6, lane = tid & 63;
  int g = lane >> 4, ln = lane & 15;
  int q0 = qb * 64;
  int qw = q0 + wave * 16;

  __shared__ bf16 Kb[2][64 * 64];
  __shared__ bf16 Vb[2][64 * 64];
  __shared__ bf16 Bb[2][64 * 64];
  __shared__ bf16 Pld[4][16 * 72];

  const bf16* qbase = qu + ((size_t)(qw + ln) * 4 + b) * 1024 + h * 64;
  bf16x8 aq0 = *(const bf16x8*)(qbase + g * 8);
  bf16x8 aq1 = *(const bf16x8*)(qbase + 32 + g * 8);

  int nk = qb + 9;

  auto issue = [&](int buf, int kt) {
    int k0 = kt * 64;
#pragma unroll
    for (int j = 0; j < 2; j++) {
      int i = tid + 256 * j;
      int r = i >> 3, c = (i & 7) ^ (r & 7);
      GLD16(&Kb[buf][i * 8], Kc + ((size_t)bh * 1024 + k0 + r) * 64 + c * 8);
    }
#pragma unroll
    for (int j = 0; j < 2; j++) {
      int i = tid + 256 * j;
      int r = i >> 3, c = (i & 7) ^ (r & 7);
      GLD16(&Vb[buf][i * 8], vT + ((size_t)bh * 64 + r) * 1024 + k0 + c * 8);
    }
#pragma unroll
    for (int j = 0; j < 2; j++) {
      int i = tid + 256 * j;
      int r = i >> 3, c = (i & 7) ^ (r & 7);
      GLD16(&Bb[buf][i * 8],
            Bsh + ((size_t)h * 2048 + (size_t)(q0 + r) * 4 + b) * 1024 + k0 + c * 8);
    }
  };

  f32x4 o[4] = {};
  float lp[4] = {0.f, 0.f, 0.f, 0.f};
  int qrow[4];
#pragma unroll
  for (int r = 0; r < 4; r++) qrow[r] = qw + g * 4 + r;

  issue(0, 0);
  for (int kt = 0; kt < nk; kt++) {
    __syncthreads();
    if (kt + 1 < nk) issue((kt + 1) & 1, kt + 1);
    const bf16* kb = Kb[kt & 1];
    const bf16* vb = Vb[kt & 1];
    const bf16* bb = Bb[kt & 1];
    int k0 = kt * 64;
#pragma unroll
    for (int s = 0; s < 4; s++) {
      int krow = s * 16 + ln;
      int sw = krow & 7;
      bf16x8 kb0 = *(const bf16x8*)(kb + krow * 64 + (g ^ sw) * 8);
      bf16x8 kb1 = *(const bf16x8*)(kb + krow * 64 + ((g + 4) ^ sw) * 8);
      f32x4 c = {0.f, 0.f, 0.f, 0.f};
      c = mfma16(aq0, kb0, c);
      c = mfma16(aq1, kb1, c);
      int k = k0 + s * 16 + ln;
#pragma unroll
      for (int r = 0; r < 4; r++) {
        int qr = wave * 16 + g * 4 + r;
        int col = s * 16 + ln;
        int ch = (col >> 3) ^ (qr & 7);
        float pb = (float)bb[qr * 64 + ch * 8 + (col & 7)];
        float P = (k <= qrow[r] + 512) ? __expf((c[r] + pb) * 0.125f) : 0.f;
        lp[r] += P;
        Pld[wave][(g * 4 + r) * 72 + s * 16 + ln] = (bf16)P;
      }
    }
    bf16x8 pa0 = *(const bf16x8*)&Pld[wave][ln * 72 + g * 8];
    bf16x8 pa1 = *(const bf16x8*)&Pld[wave][ln * 72 + 32 + g * 8];
#pragma unroll
    for (int ni = 0; ni < 4; ni++) {
      int drow = ni * 16 + ln;
      int sw = drow & 7;
      bf16x8 v0 = *(const bf16x8*)(vb + drow * 64 + (g ^ sw) * 8);
      bf16x8 v1 = *(const bf16x8*)(vb + drow * 64 + ((g + 4) ^ sw) * 8);
      o[ni] = mfma16(pa0, v0, o[ni]);
      o[ni] = mfma16(pa1, v1, o[ni]);
    }
  }
#pragma unroll
  for (int off = 1; off < 16; off <<= 1)
#pragma unroll
    for (int r = 0; r < 4; r++) lp[r] += __shfl_xor(lp[r], off, 64);
#pragma unroll
  for (int r = 0; r < 4; r++) {
    float inv = 1.f / lp[r];
    bf16* dst = av + ((size_t)qrow[r] * 4 + b) * 1024 + h * 64;
#pragma unroll
    for (int ni = 0; ni < 4; ni++) dst[ni * 16 + ln] = (bf16)(o[ni][r] * inv);
  }
}

// ------- GRU combine (+fused split-K tanh reduce) + LayerNorm2 -------------
__global__ __launch_bounds__(256) void gru_combine_ln(const float* z, const float* p0,
                                                      const float* p1, const float* x,
                                                      const float* g, const float* b,
                                                      float* o1, bf16* x2, bf16* o1b) {
  int row = blockIdx.x, tid = threadIdx.x;
  size_t base = (size_t)row * 1024 + tid * 4;
  float4 zv = *(const float4*)(z + base);
  float4 a0 = *(const float4*)(p0 + base);
  float4 a1 = *(const float4*)(p1 + base);
  float4 xv = *(const float4*)(x + base);
  float4 hv;
  hv.x = tanhf(a0.x + a1.x); hv.y = tanhf(a0.y + a1.y);
  hv.z = tanhf(a0.z + a1.z); hv.w = tanhf(a0.w + a1.w);
  float4 ov;
  ov.x = (1.f - zv.x) * xv.x + zv.x * hv.x;
  ov.y = (1.f - zv.y) * xv.y + zv.y * hv.y;
  ov.z = (1.f - zv.z) * xv.z + zv.z * hv.z;
  ov.w = (1.f - zv.w) * xv.w + zv.w * hv.w;
  *(float4*)(o1 + base) = ov;
  bf16x4 ob; ob[0] = (bf16)ov.x; ob[1] = (bf16)ov.y; ob[2] = (bf16)ov.z; ob[3] = (bf16)ov.w;
  *(bf16x4*)(o1b + (size_t)row * 2048 + tid * 4) = ob;
  float s = ov.x + ov.y + ov.z + ov.w;
  float s2 = ov.x * ov.x + ov.y * ov.y + ov.z * ov.z + ov.w * ov.w;
#pragma unroll
  for (int off = 1; off < 64; off <<= 1) { s += __shfl_xor(s, off, 64); s2 += __shfl_xor(s2, off, 64); }
  __shared__ float red[8];
  int wave = tid >> 6, lane = tid & 63;
  if (lane == 0) { red[wave] = s; red[4 + wave] = s2; }
  __syncthreads();
  s = red[0] + red[1] + red[2] + red[3];
  s2 = red[4] + red[5] + red[6] + red[7];
  float mean = s * (1.f / 1024.f);
  float var = s2 * (1.f / 1024.f) - mean * mean;
  float rstd = rsqrtf(var + 1e-5f);
  float4 gv = *(const float4*)(g + tid * 4);
  float4 bv = *(const float4*)(b + tid * 4);
  bf16x4 xo;
  xo[0] = (bf16)((ov.x - mean) * rstd * gv.x + bv.x);
  xo[1] = (bf16)((ov.y - mean) * rstd * gv.y + bv.y);
  xo[2] = (bf16)((ov.z - mean) * rstd * gv.z + bv.z);
  xo[3] = (bf16)((ov.w - mean) * rstd * gv.w + bv.w);
  *(bf16x4*)(x2 + base) = xo;
}

__global__ void final_combine(const float* z, const float* p0, const float* p1,
                              const float* o1, float* out, int n) {
  int i = (blockIdx.x * 256 + threadIdx.x) * 4;
  if (i >= n) return;
  float4 zv = *(const float4*)(z + i);
  float4 a0 = *(const float4*)(p0 + i);
  float4 a1 = *(const float4*)(p1 + i);
  float4 xv = *(const float4*)(o1 + i);
  float4 o;
  o.x = (1.f - zv.x) * xv.x + zv.x * tanhf(a0.x + a1.x);
  o.y = (1.f - zv.y) * xv.y + zv.y * tanhf(a0.y + a1.y);
  o.z = (1.f - zv.z) * xv.z + zv.z * tanhf(a0.z + a1.z);
  o.w = (1.f - zv.w) * xv.w + zv.w * tanhf(a0.w + a1.w);
  *(float4*)(out + i) = o;
}

// ---------------- host ----------------
extern "C" void kernel_launch(void* const* d_in, const int* in_sizes, int n_in,
                              void* d_out, int out_size, void* d_ws, size_t ws_size,
                              hipStream_t stream) {
  (void)in_sizes; (void)n_in; (void)out_size; (void)ws_size;
  const float* inputs  = (const float*)d_in[0];
  const float* memory  = (const float*)d_in[1];
  const float* pos_emb = (const float*)d_in[2];
  const float* u_in    = (const float*)d_in[3];
  const float* v_in    = (const float*)d_in[4];
  const float* W_kv    = (const float*)d_in[5];
  const float* b_kv    = (const float*)d_in[6];
  const float* W_q     = (const float*)d_in[7];
  const float* b_q     = (const float*)d_in[8];
  const float* W_proj  = (const float*)d_in[9];
  const float* b_proj  = (const float*)d_in[10];
  const float* W_pos   = (const float*)d_in[11];
  const float* b_pos   = (const float*)d_in[12];
  const float* ln1_g   = (const float*)d_in[13];
  const float* ln1_b   = (const float*)d_in[14];
  const float* ln2_g   = (const float*)d_in[15];
  const float* ln2_b   = (const float*)d_in[16];
  const float* Wr1 = (const float*)d_in[17];
  const float* Ur1 = (const float*)d_in[18];
  const float* Wz1 = (const float*)d_in[19];
  const float* Uz1 = (const float*)d_in[20];
  const float* Wg1 = (const float*)d_in[21];
  const float* Ug1 = (const float*)d_in[22];
  const float* bg1 = (const float*)d_in[23];
  const float* Wr2 = (const float*)d_in[24];
  const float* Ur2 = (const float*)d_in[25];
  const float* Wz2 = (const float*)d_in[26];
  const float* Uz2 = (const float*)d_in[27];
  const float* Wg2 = (const float*)d_in[28];
  const float* Ug2 = (const float*)d_in[29];
  const float* bg2 = (const float*)d_in[30];
  const float* W1  = (const float*)d_in[31];
  const float* b1  = (const float*)d_in[32];
  const float* W2  = (const float*)d_in[33];
  const float* b2  = (const float*)d_in[34];

  char* ws = (char*)d_ws;
  size_t off = 0;
  auto alloc = [&](size_t bytes) -> char* {
    char* p = ws + off;
    off += (bytes + 255) & ~(size_t)255;
    return p;
  };
  bf16* x1      = (bf16*)alloc(4096ull * 1024 * 2);
  bf16* Wkv_t   = (bf16*)alloc(2048ull * 1024 * 2);
  bf16* Wq_t    = (bf16*)alloc(1024ull * 1024 * 2);
  bf16* Wpos_t  = (bf16*)alloc(1024ull * 1024 * 2);
  bf16* Wproj_t = (bf16*)alloc(1024ull * 1024 * 2);
  bf16* Bzr1    = (bf16*)alloc(2048ull * 2048 * 2);
  bf16* Bg1     = (bf16*)alloc(1024ull * 2048 * 2);
  bf16* Bzr2    = (bf16*)alloc(2048ull * 2048 * 2);
  bf16* Bg2     = (bf16*)alloc(1024ull * 2048 * 2);
  bf16* W1t     = (bf16*)alloc(4096ull * 1024 * 2);
  bf16* W2t     = (bf16*)alloc(1024ull * 4096 * 2);
  bf16* posb    = (bf16*)alloc(1024ull * 1024 * 2);
  bf16* kvb     = (bf16*)alloc(4096ull * 2048 * 2);
  bf16* qu      = (bf16*)alloc(2048ull * 1024 * 2);
  bf16* qv      = (bf16*)alloc(2048ull * 1024 * 2);
  bf16* rb      = (bf16*)alloc(1024ull * 1024 * 2);
  bf16* Kc      = (bf16*)alloc(64ull * 1024 * 64 * 2);
  bf16* vT      = (bf16*)alloc(64ull * 64 * 1024 * 2);
  bf16* av      = (bf16*)alloc(2048ull * 1024 * 2);
  bf16* acat1   = (bf16*)alloc(2048ull * 2048 * 2);
  bf16* acat2   = (bf16*)alloc(2048ull * 2048 * 2);
  bf16* x2      = (bf16*)alloc(2048ull * 1024 * 2);
  char* arena   = alloc(64ull << 20);
  bf16*  Bshift = (bf16*)arena;                   // [h][q*4+b][k] until flash
  float* zf    = (float*)arena;                   // [0,8M)
  bf16*  rxbuf = (bf16*)(arena + (8ull << 20));   // [8,12M): r*x bf16 2048x1024
  float* o1    = (float*)(arena + (24ull << 20)); // [24,32M)
  bf16*  tffn  = (bf16*)(arena + (32ull << 20));  // [32,48M)
  float* part  = (float*)(arena + (48ull << 20)); // [48,64M): 2x 2048x1024 f32

  TPack tp;
  int di = 0;
  auto setd = [&](const float* s, bf16* d, int K, int N, int ldd) {
    tp.d[di].src = s; tp.d[di].dst = d; tp.d[di].K = K; tp.d[di].N = N; tp.d[di].ldd = ldd; di++;
  };
  setd(W_kv, Wkv_t, 1024, 2048, 1024);
  setd(W_q, Wq_t, 1024, 1024, 1024);
  setd(W_pos, Wpos_t, 1024, 1024, 1024);
  setd(W_proj, Wproj_t, 1024, 1024, 1024);
  setd(Wz1, Bzr1, 1024, 1024, 2048);              setd(Uz1, Bzr1 + 1024, 1024, 1024, 2048);
  setd(Wr1, Bzr1 + 1024ull * 2048, 1024, 1024, 2048); setd(Ur1, Bzr1 + 1024ull * 2048 + 1024, 1024, 1024, 2048);
  setd(Wg1, Bg1, 1024, 1024, 2048);               setd(Ug1, Bg1 + 1024, 1024, 1024, 2048);
  setd(Wz2, Bzr2, 1024, 1024, 2048);              setd(Uz2, Bzr2 + 1024, 1024, 1024, 2048);
  setd(Wr2, Bzr2 + 1024ull * 2048, 1024, 1024, 2048); setd(Ur2, Bzr2 + 1024ull * 2048 + 1024, 1024, 1024, 2048);
  setd(Wg2, Bg2, 1024, 1024, 2048);               setd(Ug2, Bg2 + 1024, 1024, 1024, 2048);
  setd(W1, W1t, 1024, 4096, 1024);
  setd(W2, W2t, 4096, 1024, 4096);
  wt_transpose<<<dim3(1024, 1, 18), 256, 0, stream>>>(tp);
  convertf2b<<<1024, 256, 0, stream>>>(pos_emb, posb, 1024 * 1024);
  ln1_kernel<<<4096, 256, 0, stream>>>(inputs, memory, ln1_g, ln1_b, x1, acat1 + 1024);

  auto gemm = [&](const bf16* A, int lda, const bf16* B, int ldb,
                  bf16* Cb, bf16* Cb2, float* Cf, float* Cf2, int ldc,
                  int M, int N, int K, const float* bias, int mode,
                  int bat, int S, long long Ab, long long Bb, long long Cbt,
                  const float* up, const float* vp,
                  const bf16* A2 = nullptr, int lda2 = 0) {
    GemmP p;
    p.A = A; p.A2 = A2; p.B = B; p.Cb = Cb; p.Cb2 = Cb2; p.Cf = Cf; p.Cf2 = Cf2;
    p.bias = bias; p.up = up; p.vp = vp;
    p.K = K; p.lda = lda; p.lda2 = lda2; p.ldb = ldb; p.ldc = ldc;
    p.Abat = Ab; p.Bbat = Bb; p.Cbat = Cbt; p.mode = mode;
    p.S = S; p.Ksl = K / S;
    if (mode == M_SHIFT)
      gemm_v4<64, 64, 128><<<dim3(M / 64, N / 64, bat * S), 128, 0, stream>>>(p);
    else
      gemm_v6<<<dim3(M / 128, N / 64, bat * S), 256, 0, stream>>>(p);
  };

  // projections
  gemm(x1, 1024, Wkv_t, 1024, kvb, nullptr, nullptr, nullptr, 2048, 4096, 2048, 1024, b_kv, M_BF16, 1, 1, 0, 0, 0, nullptr, nullptr);
  gemm(x1 + 2048ull * 1024, 1024, Wq_t, 1024, qu, qv, nullptr, nullptr, 1024, 2048, 1024, 1024, b_q, M_QUV, 1, 1, 0, 0, 0, u_in, v_in);
  gemm(posb, 1024, Wpos_t, 1024, rb, nullptr, nullptr, nullptr, 1024, 1024, 1024, 1024, b_pos, M_BF16, 1, 1, 0, 0, 0, nullptr, nullptr);
  kv_reorder<<<dim3(16, 64), 256, 0, stream>>>(kvb, Kc, vT);
  // Bshift[h][m][k] = (qv_h @ r_h^T) rel-shifted in vectorized epilogue (K=64 -> v4)
  gemm(qv, 1024, rb, 1024, Bshift, nullptr, nullptr, nullptr, 1024, 2048, 1024, 64, nullptr, M_SHIFT, 16, 1, 64, 64, 2048ll * 1024, nullptr, nullptr);
  flash_attn<<<dim3(8, 64), 256, 0, stream>>>(qu, Kc, vT, Bshift, av);
  // a1 = relu(av @ Wproj + b) into acat1 cols [0,1024)
  gemm(av, 1024, Wproj_t, 1024, acat1, nullptr, nullptr, nullptr, 2048, 2048, 1024, 1024, b_proj, M_BF16_RELU, 1, 1, 0, 0, 0, nullptr, nullptr);
  // GRU1: z|r GEMM with fused r*x -> rxbuf
  gemm(acat1, 2048, Bzr1, 2048, rxbuf, nullptr, zf, nullptr, 1024, 2048, 2048, 2048, bg1, M_ZRX, 1, 1, 0, 0, 0, inputs, nullptr);
  // g1: split-K=2, slice1 reads rxbuf
  gemm(acat1, 2048, Bg1, 2048, nullptr, nullptr, part, nullptr, 1024, 2048, 1024, 2048, nullptr, M_F32, 1, 2, 0, 0, 2048ll * 1024, nullptr, nullptr, rxbuf, 1024);
  gru_combine_ln<<<2048, 256, 0, stream>>>(zf, part, part + 2048ull * 1024, inputs, ln2_g, ln2_b, o1, x2, acat2 + 1024);
  // FFN
  gemm(x2, 1024, W1t, 1024, tffn, nullptr, nullptr, nullptr, 4096, 2048, 4096, 1024, b1, M_BF16_RELU, 1, 1, 0, 0, 0, nullptr, nullptr);
  gemm(tffn, 4096, W2t, 4096, nullptr, nullptr, part, nullptr, 1024, 2048, 1024, 4096, nullptr, M_F32, 1, 2, 0, 0, 2048ll * 1024, nullptr, nullptr);
  reduce2<<<2048, 256, 0, stream>>>(part, part + 2048ull * 1024, b2, acat2, 2048, 2048 * 1024);
  // GRU2
  gemm(acat2, 2048, Bzr2, 2048, rxbuf, nullptr, zf, nullptr, 1024, 2048, 2048, 2048, bg2, M_ZRX, 1, 1, 0, 0, 0, o1, nullptr);
  gemm(acat2, 2048, Bg2, 2048, nullptr, nullptr, part, nullptr, 1024, 2048, 1024, 2048, nullptr, M_F32, 1, 2, 0, 0, 2048ll * 1024, nullptr, nullptr, rxbuf, 1024);
  final_combine<<<2048, 256, 0, stream>>>(zf, part, part + 2048ull * 1024, o1, (float*)d_out, 2048 * 1024);
}

// Round 9
// 579.557 us; speedup vs baseline: 1.7448x; 1.0460x over previous
//
#include <hip/hip_runtime.h>
#include <math.h>

typedef __bf16 bf16;
typedef __bf16 bf16x8 __attribute__((ext_vector_type(8)));
typedef __bf16 bf16x4 __attribute__((ext_vector_type(4)));
typedef __bf16 bf16x2 __attribute__((ext_vector_type(2)));
typedef float f32x4 __attribute__((ext_vector_type(4)));

__device__ __forceinline__ float sigmoid_(float x) { return 1.f / (1.f + __expf(-x)); }
__device__ __forceinline__ f32x4 mfma16(bf16x8 a, bf16x8 b, f32x4 c) {
  return __builtin_amdgcn_mfma_f32_16x16x32_bf16(a, b, c, 0, 0, 0);
}

// async global->LDS, 16B per lane. LDS dest must be wave-uniform base + lane*16.
#define GLD16(ldsp, gp)                                                        \
  __builtin_amdgcn_global_load_lds(                                            \
      (__attribute__((address_space(1))) void*)(gp),                           \
      (__attribute__((address_space(3))) void*)(ldsp), 16, 0, 0)

enum { M_F32 = 0, M_BF16 = 1, M_BF16_RELU = 2, M_SIG = 3, M_SIG_NEG = 4,
       M_TANH = 5, M_QUV = 6, M_ZR = 7, M_POS = 8, M_ZRX = 9 };

struct GemmP {
  const bf16* A; const bf16* A2; const bf16* B;
  bf16* Cb; bf16* Cb2; float* Cf; float* Cf2;
  const float* bias; const float* up; const float* vp;
  int K, lda, lda2, ldb, ldc;
  long long Abat, Bbat, Cbat;
  int mode, S, Ksl;
};

__device__ __forceinline__ void epilogue_store(const GemmP& p, long long cb, bool part,
                                               int row, int col, float a) {
  long long ro = cb + (long long)row * p.ldc;
  if (part) { p.Cf[ro + col] = a; return; }
  float bv = p.bias ? p.bias[col] : 0.f;
  switch (p.mode) {
    case M_F32: p.Cf[ro + col] = a + bv; break;
    case M_BF16: p.Cb[ro + col] = (bf16)(a + bv); break;
    case M_BF16_RELU: { float t = a + bv; p.Cb[ro + col] = (bf16)(t > 0.f ? t : 0.f); } break;
    case M_SIG: p.Cf[ro + col] = sigmoid_(a + bv); break;
    case M_TANH: p.Cf[ro + col] = tanhf(a + bv); break;
    case M_QUV: {
      float t = a + bv;
      p.Cb[ro + col] = (bf16)(t + p.up[col]);
      p.Cb2[ro + col] = (bf16)(t + p.vp[col]);
    } break;
    case M_ZR: {
      if (col < 1024) p.Cf[(long long)row * 1024 + col] = sigmoid_(a - p.bias[col]);
      else p.Cf2[(long long)row * 1024 + col - 1024] = sigmoid_(a);
    } break;
    case M_ZRX: {  // z -> Cf ; r*x -> Cb (rxbuf, 1024-wide), x fp32 in p.up
      if (col < 1024) p.Cf[(long long)row * 1024 + col] = sigmoid_(a - p.bias[col]);
      else {
        int c2 = col - 1024;
        long long xo = (long long)row * 1024 + c2;
        p.Cb[xo] = (bf16)(sigmoid_(a) * p.up[xo]);
      }
    } break;
    default: break;
  }
}

// ---- GEMM v6: 128x64 tile, BK=128, single-buffered GLD16, XOR-16 swizzle ---
// B in (N,K). 4 waves, wave = 32x64. Ksl must be a multiple of 128.
// Split-K slice 1 may use a separate A matrix (p.A2/lda2) for fused GRU-g.
__global__ __launch_bounds__(256, 3) void gemm_v6(GemmP p) {
  __shared__ bf16 As[128 * 128];  // 32 KB
  __shared__ bf16 Bs[64 * 128];   // 16 KB
  const int tid = threadIdx.x;
  const int wave = tid >> 6, lane = tid & 63;
  const int g = lane >> 4, ln = lane & 15;
  const int bz = blockIdx.z;
  const int batch = bz / p.S, slice = bz % p.S;
  const bf16* A; int lda;
  if (slice == 1 && p.A2) { A = p.A2; lda = p.lda2; }
  else { A = p.A + (long long)batch * p.Abat + (long long)slice * p.Ksl; lda = p.lda; }
  const bf16* B = p.B + (long long)batch * p.Bbat + (long long)slice * p.Ksl;
  const int m0 = blockIdx.x * 128, n0 = blockIdx.y * 64;
  const int niters = p.Ksl >> 7;

  f32x4 acc[2][4] = {};
  for (int it = 0; it < niters; it++) {
    const int k0 = it << 7;
    __syncthreads();  // previous tile's LDS reads complete
#pragma unroll
    for (int j = 0; j < 8; j++) {
      int i = tid + 256 * j;
      int r = i >> 4, c = (i & 15) ^ (r & 15);
      GLD16(As + i * 8, A + (long long)(m0 + r) * lda + k0 + c * 8);
    }
#pragma unroll
    for (int j = 0; j < 4; j++) {
      int i = tid + 256 * j;
      int r = i >> 4, c = (i & 15) ^ (r & 15);
      GLD16(Bs + i * 8, B + (long long)(n0 + r) * p.ldb + k0 + c * 8);
    }
    __syncthreads();  // drain staging
#pragma unroll
    for (int kh = 0; kh < 4; kh++) {
      bf16x8 af[2], bfm[4];
#pragma unroll
      for (int mi = 0; mi < 2; mi++) {
        int row = wave * 32 + mi * 16 + ln;
        int slot = (kh * 4 + g) ^ (row & 15);
        af[mi] = *(const bf16x8*)(As + row * 128 + slot * 8);
      }
#pragma unroll
      for (int ni = 0; ni < 4; ni++) {
        int row = ni * 16 + ln;
        int slot = (kh * 4 + g) ^ (row & 15);
        bfm[ni] = *(const bf16x8*)(Bs + row * 128 + slot * 8);
      }
#pragma unroll
      for (int mi = 0; mi < 2; mi++)
#pragma unroll
        for (int ni = 0; ni < 4; ni++)
          acc[mi][ni] = mfma16(af[mi], bfm[ni], acc[mi][ni]);
    }
  }

  const long long cb = (long long)bz * p.Cbat;
  const bool part = (p.S > 1) && (p.mode == M_F32);
#pragma unroll
  for (int mi = 0; mi < 2; mi++)
#pragma unroll
    for (int r = 0; r < 4; r++) {
      int row = m0 + wave * 32 + mi * 16 + g * 4 + r;
#pragma unroll
      for (int ni = 0; ni < 4; ni++)
        epilogue_store(p, cb, part, row, n0 + ni * 16 + ln, acc[mi][ni][r]);
    }
}

// ---------------- GEMM v4 (M_POS / K=64 path): BK=64, GLD16 dbuf -----------
template <int BM, int BN, int T>
__global__ __launch_bounds__(T, 2) void gemm_v4(GemmP p) {
  constexpr int AISS = BM * 8 / T;
  constexpr int BISS = BN * 8 / T;
  constexpr int NW = T / 64;
  constexpr int WCOLS = (BN == 128) ? 2 : 1;
  constexpr int WROWS = NW / WCOLS;
  constexpr int MI = BM / (WROWS * 16);
  __shared__ bf16 smem[2 * (BM + BN) * 64];
  bf16* Asm = smem;
  bf16* Bsm = smem + 2 * BM * 64;
  const int tid = threadIdx.x;
  const int wave = tid >> 6, lane = tid & 63;
  const int g = lane >> 4, ln = lane & 15;
  const int wr = wave / WCOLS;
  const int wc = wave % WCOLS;
  const int bz = blockIdx.z;
  const int batch = bz / p.S, slice = bz % p.S;
  const bf16* A = p.A + (long long)batch * p.Abat + (long long)slice * p.Ksl;
  const bf16* B = p.B + (long long)batch * p.Bbat + (long long)slice * p.Ksl;
  const int m0 = blockIdx.x * BM, n0 = blockIdx.y * BN;
  const int niters = p.Ksl >> 6;

  auto issue = [&](int buf, int k0) {
#pragma unroll
    for (int j = 0; j < AISS; j++) {
      int i = tid + T * j;
      int r = i >> 3, c = (i & 7) ^ (r & 7);
      GLD16(Asm + buf * BM * 64 + i * 8, A + (long long)(m0 + r) * p.lda + k0 + c * 8);
    }
#pragma unroll
    for (int j = 0; j < BISS; j++) {
      int i = tid + T * j;
      int r = i >> 3, c = (i & 7) ^ (r & 7);
      GLD16(Bsm + buf * BN * 64 + i * 8, B + (long long)(n0 + r) * p.ldb + k0 + c * 8);
    }
  };

  f32x4 acc[MI][4] = {};
  issue(0, 0);
  __syncthreads();
  for (int it = 0; it < niters; it++) {
    if (it + 1 < niters) issue((it + 1) & 1, (it + 1) << 6);
    const bf16* as = Asm + (it & 1) * BM * 64;
    const bf16* bs = Bsm + (it & 1) * BN * 64;
    bf16x8 af[MI][2], bfm[4][2];
#pragma unroll
    for (int mi = 0; mi < MI; mi++) {
      int row = wr * (16 * MI) + mi * 16 + ln;
#pragma unroll
      for (int kh = 0; kh < 2; kh++) {
        int ch = (kh * 4 + g) ^ (row & 7);
        af[mi][kh] = *(const bf16x8*)(as + row * 64 + ch * 8);
      }
    }
#pragma unroll
    for (int ni = 0; ni < 4; ni++) {
      int row = wc * 64 + ni * 16 + ln;
#pragma unroll
      for (int kh = 0; kh < 2; kh++) {
        int ch = (kh * 4 + g) ^ (row & 7);
        bfm[ni][kh] = *(const bf16x8*)(bs + row * 64 + ch * 8);
      }
    }
#pragma unroll
    for (int kh = 0; kh < 2; kh++)
#pragma unroll
      for (int mi = 0; mi < MI; mi++)
#pragma unroll
        for (int ni = 0; ni < 4; ni++)
          acc[mi][ni] = mfma16(af[mi][kh], bfm[ni][kh], acc[mi][ni]);
    __syncthreads();
  }

  const long long cb = (long long)bz * p.Cbat;

  if constexpr (BM == 64 && BN == 64) {
    if (p.mode == M_POS) {
      // LDS transpose then fully-coalesced UNSHIFTED bf16x8 row stores.
      float* Ct = (float*)smem;  // 64 x 65 f32
#pragma unroll
      for (int mi = 0; mi < MI; mi++)
#pragma unroll
        for (int r = 0; r < 4; r++) {
          int row = wave * 32 + mi * 16 + g * 4 + r;
#pragma unroll
          for (int ni = 0; ni < 4; ni++)
            Ct[row * 65 + ni * 16 + ln] = acc[mi][ni][r];
        }
      __syncthreads();
#pragma unroll
      for (int pass = 0; pass < 4; pass++) {
        int row = pass * 16 + (tid >> 3);
        int c = tid & 7;
        const float* src = Ct + row * 65 + c * 8;
        bf16x8 o;
#pragma unroll
        for (int e = 0; e < 8; e++) o[e] = (bf16)src[e];
        *(bf16x8*)(p.Cb + cb + (long long)(m0 + row) * p.ldc + n0 + c * 8) = o;
      }
      return;
    }
  }

  const bool part = (p.S > 1) && (p.mode == M_F32);
#pragma unroll
  for (int mi = 0; mi < MI; mi++)
#pragma unroll
    for (int r = 0; r < 4; r++) {
      int row = m0 + wr * (16 * MI) + mi * 16 + g * 4 + r;
#pragma unroll
      for (int ni = 0; ni < 4; ni++)
        epilogue_store(p, cb, part, row, n0 + wc * 64 + ni * 16 + ln, acc[mi][ni][r]);
    }
}

// split-K=2 partial reduce + bias + relu -> bf16 (used for FFN2)
__global__ void reduce2(const float* p0, const float* p1, const float* bias,
                        bf16* ob, int ldc, int n) {
  int i = (blockIdx.x * 256 + threadIdx.x) * 4;
  if (i >= n) return;
  float4 a = *(const float4*)(p0 + i);
  float4 b = *(const float4*)(p1 + i);
  int row = i >> 10, col = i & 1023;
  float v0 = a.x + b.x + bias[col], v1 = a.y + b.y + bias[col + 1];
  float v2 = a.z + b.z + bias[col + 2], v3 = a.w + b.w + bias[col + 3];
  bf16x4 o;
  o[0] = (bf16)(v0 > 0.f ? v0 : 0.f); o[1] = (bf16)(v1 > 0.f ? v1 : 0.f);
  o[2] = (bf16)(v2 > 0.f ? v2 : 0.f); o[3] = (bf16)(v3 > 0.f ? v3 : 0.f);
  *(bf16x4*)(ob + (size_t)row * ldc + col) = o;
}

// ---------------- weight transpose + fp32->bf16 convert ----------------
struct TDesc { const float* src; bf16* dst; int K, N, ldd; };
struct TPack { TDesc d[18]; };

__global__ __launch_bounds__(256) void wt_transpose(TPack tp) {
  TDesc t = tp.d[blockIdx.z];
  int ntx = t.N >> 6, nty = t.K >> 6;
  int tile = blockIdx.x;
  if (tile >= ntx * nty) return;
  int k0 = (tile / ntx) * 64, n0 = (tile % ntx) * 64;
  __shared__ bf16 tb[64][72];
  int tid = threadIdx.x;
  int tr = tid >> 4, tc = (tid & 15) * 4;
#pragma unroll
  for (int ph = 0; ph < 4; ph++) {
    int k = k0 + ph * 16 + tr;
    float4 vv = *(const float4*)(t.src + (size_t)k * t.N + n0 + tc);
    tb[tc + 0][ph * 16 + tr] = (bf16)vv.x;
    tb[tc + 1][ph * 16 + tr] = (bf16)vv.y;
    tb[tc + 2][ph * 16 + tr] = (bf16)vv.z;
    tb[tc + 3][ph * 16 + tr] = (bf16)vv.w;
  }
  __syncthreads();
#pragma unroll
  for (int ph = 0; ph < 4; ph++) {
    int n = ph * 16 + tr;
    bf16x4 o;
    o[0] = tb[n][tc + 0]; o[1] = tb[n][tc + 1]; o[2] = tb[n][tc + 2]; o[3] = tb[n][tc + 3];
    *(bf16x4*)(t.dst + (size_t)(n0 + n) * t.ldd + k0 + tc) = o;
  }
}

__global__ void convertf2b(const float* src, bf16* dst, int n) {
  int i = (blockIdx.x * 256 + threadIdx.x) * 4;
  if (i >= n) return;
  float4 vv = *(const float4*)(src + i);
  bf16x4 o; o[0] = (bf16)vv.x; o[1] = (bf16)vv.y; o[2] = (bf16)vv.z; o[3] = (bf16)vv.w;
  *(bf16x4*)(dst + i) = o;
}

// ---------------- LayerNorm 1 (concat(memory, inputs)) ----------------
__global__ __launch_bounds__(256) void ln1_kernel(const float* inputs, const float* memory,
                                                  const float* g, const float* b,
                                                  bf16* x1, bf16* acat1x) {
  int row = blockIdx.x;
  int tid = threadIdx.x;
  const float* src = (row < 2048) ? (memory + (size_t)row * 1024)
                                  : (inputs + (size_t)(row - 2048) * 1024);
  float4 vv = *(const float4*)(src + tid * 4);
  float s = vv.x + vv.y + vv.z + vv.w;
  float s2 = vv.x * vv.x + vv.y * vv.y + vv.z * vv.z + vv.w * vv.w;
#pragma unroll
  for (int off = 1; off < 64; off <<= 1) { s += __shfl_xor(s, off, 64); s2 += __shfl_xor(s2, off, 64); }
  __shared__ float red[8];
  int wave = tid >> 6, lane = tid & 63;
  if (lane == 0) { red[wave] = s; red[4 + wave] = s2; }
  __syncthreads();
  s = red[0] + red[1] + red[2] + red[3];
  s2 = red[4] + red[5] + red[6] + red[7];
  float mean = s * (1.f / 1024.f);
  float var = s2 * (1.f / 1024.f) - mean * mean;
  float rstd = rsqrtf(var + 1e-5f);
  float4 gv = *(const float4*)(g + tid * 4);
  float4 bv = *(const float4*)(b + tid * 4);
  bf16x4 o;
  o[0] = (bf16)((vv.x - mean) * rstd * gv.x + bv.x);
  o[1] = (bf16)((vv.y - mean) * rstd * gv.y + bv.y);
  o[2] = (bf16)((vv.z - mean) * rstd * gv.z + bv.z);
  o[3] = (bf16)((vv.w - mean) * rstd * gv.w + bv.w);
  *(bf16x4*)(x1 + (size_t)row * 1024 + tid * 4) = o;
  if (row >= 2048) {
    bf16x4 xo;
    xo[0] = (bf16)vv.x; xo[1] = (bf16)vv.y; xo[2] = (bf16)vv.z; xo[3] = (bf16)vv.w;
    *(bf16x4*)(acat1x + (size_t)(row - 2048) * 2048 + tid * 4) = xo;
  }
}

// ------- K gather (contiguous per bh) + V transpose --------
__global__ __launch_bounds__(256) void kv_reorder(const bf16* kvb, bf16* Kc, bf16* vT) {
  int bh = blockIdx.y;
  int b = bh >> 4, h = bh & 15;
  int t0 = blockIdx.x * 64;
  int tid = threadIdx.x;
  {
    int t = t0 + (tid >> 2), d8 = (tid & 3) * 8;
    bf16x8 kk = *(const bf16x8*)(kvb + ((size_t)t * 4 + b) * 2048 + h * 64 + d8);
    *(bf16x8*)(Kc + ((size_t)bh * 1024 + t) * 64 + d8) = kk;
  }
  __shared__ bf16 tile[64][72];
  int tr = tid >> 4, tc = (tid & 15) * 4;
#pragma unroll
  for (int ph = 0; ph < 4; ph++) {
    int t = t0 + ph * 16 + tr;
    const bf16* src = kvb + ((size_t)t * 4 + b) * 2048 + 1024 + h * 64 + tc;
    bf16x4 vv = *(const bf16x4*)src;
    tile[tc + 0][ph * 16 + tr] = vv[0];
    tile[tc + 1][ph * 16 + tr] = vv[1];
    tile[tc + 2][ph * 16 + tr] = vv[2];
    tile[tc + 3][ph * 16 + tr] = vv[3];
  }
  __syncthreads();
#pragma unroll
  for (int ph = 0; ph < 4; ph++) {
    int d = ph * 16 + tr;
    bf16x4 o;
    o[0] = tile[d][tc + 0]; o[1] = tile[d][tc + 1]; o[2] = tile[d][tc + 2]; o[3] = tile[d][tc + 3];
    *(bf16x4*)(vT + ((size_t)bh * 64 + d) * 1024 + t0 + tc) = o;
  }
}

// ------- fused rel-pos flash attention: block-cooperative, GLD16 dbuf -------
// Bias is read from UNSHIFTED Bpos[h][m=q*4+b][j], j = k - q + 511, ld=1152.
// Per k-tile we stage a 64x128 band: rows q0..q0+63, cols jbase..jbase+127,
// jbase = k0 - q0 + 448 (multiple of 64 -> aligned). The per-row skew is
// absorbed in the scalar LDS read: bb[qr*128 + (col - qr + 63)].
__global__ __launch_bounds__(256, 2) void flash_attn(const bf16* qu, const bf16* Kc,
                                                     const bf16* vT, const bf16* Bpos,
                                                     bf16* av) {
  int qb = blockIdx.x;
  int bh = blockIdx.y;
  int b = bh >> 4, h = bh & 15;
  int tid = threadIdx.x;
  int wave = tid >> 6, lane = tid & 63;
  int g = lane >> 4, ln = lane & 15;
  int q0 = qb * 64;
  int qw = q0 + wave * 16;

  __shared__ bf16 Kb[2][64 * 64];
  __shared__ bf16 Vb[2][64 * 64];
  __shared__ bf16 Bb[2][64 * 128];
  __shared__ bf16 Pld[4][16 * 72];

  const bf16* qbase = qu + ((size_t)(qw + ln) * 4 + b) * 1024 + h * 64;
  bf16x8 aq0 = *(const bf16x8*)(qbase + g * 8);
  bf16x8 aq1 = *(const bf16x8*)(qbase + 32 + g * 8);

  const bf16* bposbase = Bpos + (size_t)h * 2048 * 1152;
  int nk = qb + 9;

  auto issue = [&](int buf, int kt) {
    int k0 = kt * 64;
    int jbase = k0 - q0 + 448;
#pragma unroll
    for (int j = 0; j < 2; j++) {
      int i = tid + 256 * j;
      int r = i >> 3, c = (i & 7) ^ (r & 7);
      GLD16(&Kb[buf][i * 8], Kc + ((size_t)bh * 1024 + k0 + r) * 64 + c * 8);
    }
#pragma unroll
    for (int j = 0; j < 2; j++) {
      int i = tid + 256 * j;
      int r = i >> 3, c = (i & 7) ^ (r & 7);
      GLD16(&Vb[buf][i * 8], vT + ((size_t)bh * 64 + r) * 1024 + k0 + c * 8);
    }
#pragma unroll
    for (int j = 0; j < 4; j++) {
      int i = tid + 256 * j;
      int r = i >> 4, c = i & 15;  // linear band: row r, 16B chunk c
      GLD16(&Bb[buf][i * 8],
            bposbase + ((size_t)(q0 + r) * 4 + b) * 1152 + jbase + c * 8);
    }
  };

  f32x4 o[4] = {};
  float lp[4] = {0.f, 0.f, 0.f, 0.f};
  int qrow[4];
#pragma unroll
  for (int r = 0; r < 4; r++) qrow[r] = qw + g * 4 + r;

  issue(0, 0);
  for (int kt = 0; kt < nk; kt++) {
    __syncthreads();
    if (kt + 1 < nk) issue((kt + 1) & 1, kt + 1);
    const bf16* kb = Kb[kt & 1];
    const bf16* vb = Vb[kt & 1];
    const bf16* bb = Bb[kt & 1];
    int k0 = kt * 64;
#pragma unroll
    for (int s = 0; s < 4; s++) {
      int krow = s * 16 + ln;
      int sw = krow & 7;
      bf16x8 kb0 = *(const bf16x8*)(kb + krow * 64 + (g ^ sw) * 8);
      bf16x8 kb1 = *(const bf16x8*)(kb + krow * 64 + ((g + 4) ^ sw) * 8);
      f32x4 c = {0.f, 0.f, 0.f, 0.f};
      c = mfma16(aq0, kb0, c);
      c = mfma16(aq1, kb1, c);
      int k = k0 + s * 16 + ln;
#pragma unroll
      for (int r = 0; r < 4; r++) {
        int qr = wave * 16 + g * 4 + r;
        int col = s * 16 + ln;
        float pb = (float)bb[qr * 128 + col - qr + 63];
        float P = (k <= qrow[r] + 512) ? __expf((c[r] + pb) * 0.125f) : 0.f;
        lp[r] += P;
        Pld[wave][(g * 4 + r) * 72 + s * 16 + ln] = (bf16)P;
      }
    }
    bf16x8 pa0 = *(const bf16x8*)&Pld[wave][ln * 72 + g * 8];
    bf16x8 pa1 = *(const bf16x8*)&Pld[wave][ln * 72 + 32 + g * 8];
#pragma unroll
    for (int ni = 0; ni < 4; ni++) {
      int drow = ni * 16 + ln;
      int sw = drow & 7;
      bf16x8 v0 = *(const bf16x8*)(vb + drow * 64 + (g ^ sw) * 8);
      bf16x8 v1 = *(const bf16x8*)(vb + drow * 64 + ((g + 4) ^ sw) * 8);
      o[ni] = mfma16(pa0, v0, o[ni]);
      o[ni] = mfma16(pa1, v1, o[ni]);
    }
  }
#pragma unroll
  for (int off = 1; off < 16; off <<= 1)
#pragma unroll
    for (int r = 0; r < 4; r++) lp[r] += __shfl_xor(lp[r], off, 64);
#pragma unroll
  for (int r = 0; r < 4; r++) {
    float inv = 1.f / lp[r];
    bf16* dst = av + ((size_t)qrow[r] * 4 + b) * 1024 + h * 64;
#pragma unroll
    for (int ni = 0; ni < 4; ni++) dst[ni * 16 + ln] = (bf16)(o[ni][r] * inv);
  }
}

// ------- GRU combine (+fused split-K tanh reduce) + LayerNorm2 -------------
__global__ __launch_bounds__(256) void gru_combine_ln(const float* z, const float* p0,
                                                      const float* p1, const float* x,
                                                      const float* g, const float* b,
                                                      float* o1, bf16* x2, bf16* o1b) {
  int row = blockIdx.x, tid = threadIdx.x;
  size_t base = (size_t)row * 1024 + tid * 4;
  float4 zv = *(const float4*)(z + base);
  float4 a0 = *(const float4*)(p0 + base);
  float4 a1 = *(const float4*)(p1 + base);
  float4 xv = *(const float4*)(x + base);
  float4 hv;
  hv.x = tanhf(a0.x + a1.x); hv.y = tanhf(a0.y + a1.y);
  hv.z = tanhf(a0.z + a1.z); hv.w = tanhf(a0.w + a1.w);
  float4 ov;
  ov.x = (1.f - zv.x) * xv.x + zv.x * hv.x;
  ov.y = (1.f - zv.y) * xv.y + zv.y * hv.y;
  ov.z = (1.f - zv.z) * xv.z + zv.z * hv.z;
  ov.w = (1.f - zv.w) * xv.w + zv.w * hv.w;
  *(float4*)(o1 + base) = ov;
  bf16x4 ob; ob[0] = (bf16)ov.x; ob[1] = (bf16)ov.y; ob[2] = (bf16)ov.z; ob[3] = (bf16)ov.w;
  *(bf16x4*)(o1b + (size_t)row * 2048 + tid * 4) = ob;
  float s = ov.x + ov.y + ov.z + ov.w;
  float s2 = ov.x * ov.x + ov.y * ov.y + ov.z * ov.z + ov.w * ov.w;
#pragma unroll
  for (int off = 1; off < 64; off <<= 1) { s += __shfl_xor(s, off, 64); s2 += __shfl_xor(s2, off, 64); }
  __shared__ float red[8];
  int wave = tid >> 6, lane = tid & 63;
  if (lane == 0) { red[wave] = s; red[4 + wave] = s2; }
  __syncthreads();
  s = red[0] + red[1] + red[2] + red[3];
  s2 = red[4] + red[5] + red[6] + red[7];
  float mean = s * (1.f / 1024.f);
  float var = s2 * (1.f / 1024.f) - mean * mean;
  float rstd = rsqrtf(var + 1e-5f);
  float4 gv = *(const float4*)(g + tid * 4);
  float4 bv = *(const float4*)(b + tid * 4);
  bf16x4 xo;
  xo[0] = (bf16)((ov.x - mean) * rstd * gv.x + bv.x);
  xo[1] = (bf16)((ov.y - mean) * rstd * gv.y + bv.y);
  xo[2] = (bf16)((ov.z - mean) * rstd * gv.z + bv.z);
  xo[3] = (bf16)((ov.w - mean) * rstd * gv.w + bv.w);
  *(bf16x4*)(x2 + base) = xo;
}

__global__ void final_combine(const float* z, const float* p0, const float* p1,
                              const float* o1, float* out, int n) {
  int i = (blockIdx.x * 256 + threadIdx.x) * 4;
  if (i >= n) return;
  float4 zv = *(const float4*)(z + i);
  float4 a0 = *(const float4*)(p0 + i);
  float4 a1 = *(const float4*)(p1 + i);
  float4 xv = *(const float4*)(o1 + i);
  float4 o;
  o.x = (1.f - zv.x) * xv.x + zv.x * tanhf(a0.x + a1.x);
  o.y = (1.f - zv.y) * xv.y + zv.y * tanhf(a0.y + a1.y);
  o.z = (1.f - zv.z) * xv.z + zv.z * tanhf(a0.z + a1.z);
  o.w = (1.f - zv.w) * xv.w + zv.w * tanhf(a0.w + a1.w);
  *(float4*)(out + i) = o;
}

// ---------------- host ----------------
extern "C" void kernel_launch(void* const* d_in, const int* in_sizes, int n_in,
                              void* d_out, int out_size, void* d_ws, size_t ws_size,
                              hipStream_t stream) {
  (void)in_sizes; (void)n_in; (void)out_size; (void)ws_size;
  const float* inputs  = (const float*)d_in[0];
  const float* memory  = (const float*)d_in[1];
  const float* pos_emb = (const float*)d_in[2];
  const float* u_in    = (const float*)d_in[3];
  const float* v_in    = (const float*)d_in[4];
  const float* W_kv    = (const float*)d_in[5];
  const float* b_kv    = (const float*)d_in[6];
  const float* W_q     = (const float*)d_in[7];
  const float* b_q     = (const float*)d_in[8];
  const float* W_proj  = (const float*)d_in[9];
  const float* b_proj  = (const float*)d_in[10];
  const float* W_pos   = (const float*)d_in[11];
  const float* b_pos   = (const float*)d_in[12];
  const float* ln1_g   = (const float*)d_in[13];
  const float* ln1_b   = (const float*)d_in[14];
  const float* ln2_g   = (const float*)d_in[15];
  const float* ln2_b   = (const float*)d_in[16];
  const float* Wr1 = (const float*)d_in[17];
  const float* Ur1 = (const float*)d_in[18];
  const float* Wz1 = (const float*)d_in[19];
  const float* Uz1 = (const float*)d_in[20];
  const float* Wg1 = (const float*)d_in[21];
  const float* Ug1 = (const float*)d_in[22];
  const float* bg1 = (const float*)d_in[23];
  const float* Wr2 = (const float*)d_in[24];
  const float* Ur2 = (const float*)d_in[25];
  const float* Wz2 = (const float*)d_in[26];
  const float* Uz2 = (const float*)d_in[27];
  const float* Wg2 = (const float*)d_in[28];
  const float* Ug2 = (const float*)d_in[29];
  const float* bg2 = (const float*)d_in[30];
  const float* W1  = (const float*)d_in[31];
  const float* b1  = (const float*)d_in[32];
  const float* W2  = (const float*)d_in[33];
  const float* b2  = (const float*)d_in[34];

  char* ws = (char*)d_ws;
  size_t off = 0;
  auto alloc = [&](size_t bytes) -> char* {
    char* p = ws + off;
    off += (bytes + 255) & ~(size_t)255;
    return p;
  };
  bf16* x1      = (bf16*)alloc(4096ull * 1024 * 2);
  bf16* Wkv_t   = (bf16*)alloc(2048ull * 1024 * 2);
  bf16* Wq_t    = (bf16*)alloc(1024ull * 1024 * 2);
  bf16* Wpos_t  = (bf16*)alloc(1024ull * 1024 * 2);
  bf16* Wproj_t = (bf16*)alloc(1024ull * 1024 * 2);
  bf16* Bzr1    = (bf16*)alloc(2048ull * 2048 * 2);
  bf16* Bg1     = (bf16*)alloc(1024ull * 2048 * 2);
  bf16* Bzr2    = (bf16*)alloc(2048ull * 2048 * 2);
  bf16* Bg2     = (bf16*)alloc(1024ull * 2048 * 2);
  bf16* W1t     = (bf16*)alloc(4096ull * 1024 * 2);
  bf16* W2t     = (bf16*)alloc(1024ull * 4096 * 2);
  bf16* posb    = (bf16*)alloc(1024ull * 1024 * 2);
  bf16* kvb     = (bf16*)alloc(4096ull * 2048 * 2);
  bf16* qu      = (bf16*)alloc(2048ull * 1024 * 2);
  bf16* qv      = (bf16*)alloc(2048ull * 1024 * 2);
  bf16* rb      = (bf16*)alloc(1024ull * 1024 * 2);
  bf16* Kc      = (bf16*)alloc(64ull * 1024 * 64 * 2);
  bf16* vT      = (bf16*)alloc(64ull * 64 * 1024 * 2);
  bf16* av      = (bf16*)alloc(2048ull * 1024 * 2);
  bf16* acat1   = (bf16*)alloc(2048ull * 2048 * 2);
  bf16* acat2   = (bf16*)alloc(2048ull * 2048 * 2);
  bf16* x2      = (bf16*)alloc(2048ull * 1024 * 2);
  char* arena   = alloc(80ull << 20);
  bf16*  Bpos  = (bf16*)arena;                    // [h][m][j] ld=1152, 72MB, until flash
  float* zf    = (float*)arena;                   // [0,8M)   after flash
  bf16*  rxbuf = (bf16*)(arena + (8ull << 20));   // [8,12M): r*x bf16 2048x1024
  float* o1    = (float*)(arena + (24ull << 20)); // [24,32M)
  bf16*  tffn  = (bf16*)(arena + (32ull << 20));  // [32,48M)
  float* part  = (float*)(arena + (48ull << 20)); // [48,64M): 2x 2048x1024 f32

  TPack tp;
  int di = 0;
  auto setd = [&](const float* s, bf16* d, int K, int N, int ldd) {
    tp.d[di].src = s; tp.d[di].dst = d; tp.d[di].K = K; tp.d[di].N = N; tp.d[di].ldd = ldd; di++;
  };
  setd(W_kv, Wkv_t, 1024, 2048, 1024);
  setd(W_q, Wq_t, 1024, 1024, 1024);
  setd(W_pos, Wpos_t, 1024, 1024, 1024);
  setd(W_proj, Wproj_t, 1024, 1024, 1024);
  setd(Wz1, Bzr1, 1024, 1024, 2048);              setd(Uz1, Bzr1 + 1024, 1024, 1024, 2048);
  setd(Wr1, Bzr1 + 1024ull * 2048, 1024, 1024, 2048); setd(Ur1, Bzr1 + 1024ull * 2048 + 1024, 1024, 1024, 2048);
  setd(Wg1, Bg1, 1024, 1024, 2048);               setd(Ug1, Bg1 + 1024, 1024, 1024, 2048);
  setd(Wz2, Bzr2, 1024, 1024, 2048);              setd(Uz2, Bzr2 + 1024, 1024, 1024, 2048);
  setd(Wr2, Bzr2 + 1024ull * 2048, 1024, 1024, 2048); setd(Ur2, Bzr2 + 1024ull * 2048 + 1024, 1024, 1024, 2048);
  setd(Wg2, Bg2, 1024, 1024, 2048);               setd(Ug2, Bg2 + 1024, 1024, 1024, 2048);
  setd(W1, W1t, 1024, 4096, 1024);
  setd(W2, W2t, 4096, 1024, 4096);
  wt_transpose<<<dim3(1024, 1, 18), 256, 0, stream>>>(tp);
  convertf2b<<<1024, 256, 0, stream>>>(pos_emb, posb, 1024 * 1024);
  ln1_kernel<<<4096, 256, 0, stream>>>(inputs, memory, ln1_g, ln1_b, x1, acat1 + 1024);

  auto gemm = [&](const bf16* A, int lda, const bf16* B, int ldb,
                  bf16* Cb, bf16* Cb2, float* Cf, float* Cf2, int ldc,
                  int M, int N, int K, const float* bias, int mode,
                  int bat, int S, long long Ab, long long Bb, long long Cbt,
                  const float* up, const float* vp,
                  const bf16* A2 = nullptr, int lda2 = 0) {
    GemmP p;
    p.A = A; p.A2 = A2; p.B = B; p.Cb = Cb; p.Cb2 = Cb2; p.Cf = Cf; p.Cf2 = Cf2;
    p.bias = bias; p.up = up; p.vp = vp;
    p.K = K; p.lda = lda; p.lda2 = lda2; p.ldb = ldb; p.ldc = ldc;
    p.Abat = Ab; p.Bbat = Bb; p.Cbat = Cbt; p.mode = mode;
    p.S = S; p.Ksl = K / S;
    if (mode == M_POS)
      gemm_v4<64, 64, 128><<<dim3(M / 64, N / 64, bat * S), 128, 0, stream>>>(p);
    else
      gemm_v6<<<dim3(M / 128, N / 64, bat * S), 256, 0, stream>>>(p);
  };

  // projections
  gemm(x1, 1024, Wkv_t, 1024, kvb, nullptr, nullptr, nullptr, 2048, 4096, 2048, 1024, b_kv, M_BF16, 1, 1, 0, 0, 0, nullptr, nullptr);
  gemm(x1 + 2048ull * 1024, 1024, Wq_t, 1024, qu, qv, nullptr, nullptr, 1024, 2048, 1024, 1024, b_q, M_QUV, 1, 1, 0, 0, 0, u_in, v_in);
  gemm(posb, 1024, Wpos_t, 1024, rb, nullptr, nullptr, nullptr, 1024, 1024, 1024, 1024, b_pos, M_BF16, 1, 1, 0, 0, 0, nullptr, nullptr);
  kv_reorder<<<dim3(16, 64), 256, 0, stream>>>(kvb, Kc, vT);
  // Bpos[h][m][j] = qv_h @ rb_h^T, UNSHIFTED, ld=1152 (K=64 -> v4, coalesced stores)
  gemm(qv, 1024, rb, 1024, Bpos, nullptr, nullptr, nullptr, 1152, 2048, 1024, 64, nullptr, M_POS, 16, 1, 64, 64, 2048ll * 1152, nullptr, nullptr);
  flash_attn<<<dim3(8, 64), 256, 0, stream>>>(qu, Kc, vT, Bpos, av);
  // a1 = relu(av @ Wproj + b) into acat1 cols [0,1024)
  gemm(av, 1024, Wproj_t, 1024, acat1, nullptr, nullptr, nullptr, 2048, 2048, 1024, 1024, b_proj, M_BF16_RELU, 1, 1, 0, 0, 0, nullptr, nullptr);
  // GRU1: z|r GEMM with fused r*x -> rxbuf
  gemm(acat1, 2048, Bzr1, 2048, rxbuf, nullptr, zf, nullptr, 1024, 2048, 2048, 2048, bg1, M_ZRX, 1, 1, 0, 0, 0, inputs, nullptr);
  // g1: split-K=2, slice1 reads rxbuf
  gemm(acat1, 2048, Bg1, 2048, nullptr, nullptr, part, nullptr, 1024, 2048, 1024, 2048, nullptr, M_F32, 1, 2, 0, 0, 2048ll * 1024, nullptr, nullptr, rxbuf, 1024);
  gru_combine_ln<<<2048, 256, 0, stream>>>(zf, part, part + 2048ull * 1024, inputs, ln2_g, ln2_b, o1, x2, acat2 + 1024);
  // FFN
  gemm(x2, 1024, W1t, 1024, tffn, nullptr, nullptr, nullptr, 4096, 2048, 4096, 1024, b1, M_BF16_RELU, 1, 1, 0, 0, 0, nullptr, nullptr);
  gemm(tffn, 4096, W2t, 4096, nullptr, nullptr, part, nullptr, 1024, 2048, 1024, 4096, nullptr, M_F32, 1, 2, 0, 0, 2048ll * 1024, nullptr, nullptr);
  reduce2<<<2048, 256, 0, stream>>>(part, part + 2048ull * 1024, b2, acat2, 2048, 2048 * 1024);
  // GRU2
  gemm(acat2, 2048, Bzr2, 2048, rxbuf, nullptr, zf, nullptr, 1024, 2048, 2048, 2048, bg2, M_ZRX, 1, 1, 0, 0, 0, o1, nullptr);
  gemm(acat2, 2048, Bg2, 2048, nullptr, nullptr, part, nullptr, 1024, 2048, 1024, 2048, nullptr, M_F32, 1, 2, 0, 0, 2048ll * 1024, nullptr, nullptr, rxbuf, 1024);
  final_combine<<<2048, 256, 0, stream>>>(zf, part, part + 2048ull * 1024, o1, (float*)d_out, 2048 * 1024);
}